// Round 1
// baseline (917.926 us; speedup 1.0000x reference)
//
#include <hip/hip_runtime.h>
#include <math.h>

namespace {

constexpr int N = 50000;
constexpr int E = 800000;

// ---------- CSR build ----------

__global__ void zero_int(int* p, int n) {
  int i = blockIdx.x * blockDim.x + threadIdx.x;
  if (i < n) p[i] = 0;
}

__global__ void count_deg(const int* __restrict__ dst, int* __restrict__ cnt, int e) {
  int i = blockIdx.x * blockDim.x + threadIdx.x;
  if (i < e) atomicAdd(&cnt[dst[i]], 1);
}

__global__ void block_sums(const int* __restrict__ cnt, int* __restrict__ bsum, int n) {
  int tid = threadIdx.x;
  int i = blockIdx.x * 256 + tid;
  int v = (i < n) ? cnt[i] : 0;
  for (int off = 32; off > 0; off >>= 1) v += __shfl_down(v, off, 64);
  __shared__ int sred[4];
  if ((tid & 63) == 0) sred[tid >> 6] = v;
  __syncthreads();
  if (tid == 0) bsum[blockIdx.x] = sred[0] + sred[1] + sred[2] + sred[3];
}

__global__ void scan_bsums(int* bsum, int nb) {
  if (threadIdx.x == 0 && blockIdx.x == 0) {
    int run = 0;
    for (int b = 0; b < nb; ++b) { int t = bsum[b]; bsum[b] = run; run += t; }
  }
}

__global__ void scan_chunks(const int* __restrict__ cnt, const int* __restrict__ bsum,
                            int* __restrict__ row_ptr, int* __restrict__ cursor, int n) {
  __shared__ int s[256];
  int tid = threadIdx.x;
  int i = blockIdx.x * 256 + tid;
  int v = (i < n) ? cnt[i] : 0;
  s[tid] = v;
  __syncthreads();
  for (int d = 1; d < 256; d <<= 1) {
    int t = (tid >= d) ? s[tid - d] : 0;
    __syncthreads();
    s[tid] += t;
    __syncthreads();
  }
  if (i < n) {
    int excl = bsum[blockIdx.x] + s[tid] - v;
    row_ptr[i] = excl;
    cursor[i] = excl;
    if (i == n - 1) row_ptr[n] = excl + v;
  }
}

__global__ void compute_dinv(const int* __restrict__ cnt, float* __restrict__ dinv, int n) {
  int i = blockIdx.x * blockDim.x + threadIdx.x;
  if (i < n) dinv[i] = rsqrtf((float)(cnt[i] + 1));  // +1 for self-loop; deg>=1 always
}

__global__ void scatter_edges(const int* __restrict__ src, const int* __restrict__ dst,
                              int* __restrict__ cursor, int* __restrict__ csr_src, int e) {
  int i = blockIdx.x * blockDim.x + threadIdx.x;
  if (i < e) {
    int d = dst[i];
    int pos = atomicAdd(&cursor[d], 1);
    csr_src[pos] = src[i];
  }
}

// ---------- weight concat for [W_mean | W_logvar] ----------

__global__ void make_wcat(const float* __restrict__ Wm, const float* __restrict__ Wl,
                          const float* __restrict__ bm, const float* __restrict__ bl,
                          float* __restrict__ Wcat, float* __restrict__ bcat) {
  int idx = blockIdx.x * blockDim.x + threadIdx.x;
  if (idx < 128 * 128) {
    int k = idx >> 7, j = idx & 127;
    Wcat[idx] = (j < 64) ? Wm[k * 64 + j] : Wl[k * 64 + (j - 64)];
  }
  if (idx < 64) bcat[idx] = bm[idx];
  else if (idx < 128) bcat[idx] = bl[idx - 64];
}

// ---------- GEMM: C[n x 128] = A[n x K] @ W[K x 128] ----------

template <int K>
__global__ void gemm128(const float* __restrict__ A, const float* __restrict__ W,
                        float* __restrict__ C, int n) {
  __shared__ float As[2][K];
  int tid = threadIdx.x;
  int r0 = blockIdx.x * 2;
  for (int t = tid; t < 2 * K; t += 256) {
    int r = t / K, k = t - r * K;
    int gr = r0 + r;
    As[r][k] = (gr < n) ? A[(long)gr * K + k] : 0.f;
  }
  __syncthreads();
  int row = r0 + (tid >> 7);
  int j = tid & 127;
  if (row >= n) return;
  const float* a = As[tid >> 7];
  float acc = 0.f;
#pragma unroll
  for (int k = 0; k < K; ++k) acc = fmaf(a[k], W[k * 128 + j], acc);
  C[(long)row * 128 + j] = acc;
}

// C = A1 @ W[0:128] + A2 @ W[128:256], W is 256x128
__global__ void gemm_cat(const float* __restrict__ A1, const float* __restrict__ A2,
                         const float* __restrict__ W, float* __restrict__ C, int n) {
  __shared__ float As1[2][128];
  __shared__ float As2[2][128];
  int tid = threadIdx.x;
  int r0 = blockIdx.x * 2;
  {
    int r = tid >> 7, k = tid & 127;
    int gr = r0 + r;
    As1[r][k] = (gr < n) ? A1[(long)gr * 128 + k] : 0.f;
    As2[r][k] = (gr < n) ? A2[(long)gr * 128 + k] : 0.f;
  }
  __syncthreads();
  int row = r0 + (tid >> 7);
  int j = tid & 127;
  if (row >= n) return;
  const float* a1 = As1[tid >> 7];
  const float* a2 = As2[tid >> 7];
  float acc = 0.f;
#pragma unroll
  for (int k = 0; k < 128; ++k) acc = fmaf(a1[k], W[k * 128 + j], acc);
#pragma unroll
  for (int k = 0; k < 128; ++k) acc = fmaf(a2[k], W[(128 + k) * 128 + j], acc);
  C[(long)row * 128 + j] = acc;
}

// ---------- propagation: Y[i] = act( dinv[i]*(sum_in dinv[s]*X[s] + dinv[i]*X[i]) + b ) ----------

__global__ void prop128(const float* __restrict__ X, float* __restrict__ Y,
                        const int* __restrict__ row_ptr, const int* __restrict__ csr_src,
                        const float* __restrict__ dinv, const float* __restrict__ bias,
                        int n, int act) {
  int i = blockIdx.x;
  int j = threadIdx.x;  // 128 threads, one column each
  float di = dinv[i];
  float acc = di * X[(long)i * 128 + j];  // self-loop (will be scaled by di again below)
  int e0 = row_ptr[i], e1 = row_ptr[i + 1];
  for (int e = e0; e < e1; ++e) {
    int s = csr_src[e];
    acc = fmaf(dinv[s], X[(long)s * 128 + j], acc);
  }
  float v = di * acc + bias[j];
  Y[(long)i * 128 + j] = act ? tanhf(v) : v;
}

// ---------- epilogue: z = noise*exp(0.5*logvar)+mean; out = [z | mean | logvar] ----------

__global__ void finalize(const float* __restrict__ ML, const float* __restrict__ noise,
                         float* __restrict__ out, int n) {
  int idx = blockIdx.x * blockDim.x + threadIdx.x;
  if (idx >= n * 64) return;
  int i = idx >> 6, j = idx & 63;
  float mean = ML[(long)i * 128 + j];
  float logvar = ML[(long)i * 128 + 64 + j];
  float z = fmaf(noise[idx], expf(0.5f * logvar), mean);
  out[idx] = z;
  out[(long)n * 64 + idx] = mean;
  out[(long)2 * n * 64 + idx] = logvar;
}

}  // namespace

extern "C" void kernel_launch(void* const* d_in, const int* in_sizes, int n_in,
                              void* d_out, int out_size, void* d_ws, size_t ws_size,
                              hipStream_t stream) {
  const float* feature   = (const float*)d_in[0];
  const float* condition = (const float*)d_in[1];
  const int*   ei        = (const int*)d_in[2];
  const float* noise     = (const float*)d_in[3];
  const float* W_f2h     = (const float*)d_in[4];
  const float* b_f2h     = (const float*)d_in[5];
  const float* W_c2h     = (const float*)d_in[6];
  const float* b_c2h     = (const float*)d_in[7];
  const float* W_h2h     = (const float*)d_in[8];
  const float* b_h2h     = (const float*)d_in[9];
  const float* W_mean    = (const float*)d_in[10];
  const float* b_mean    = (const float*)d_in[11];
  const float* W_logvar  = (const float*)d_in[12];
  const float* b_logvar  = (const float*)d_in[13];

  const int* src = ei;        // edge_index[0]
  const int* dst = ei + E;    // edge_index[1]

  char* p = (char*)d_ws;
  auto alloc = [&](size_t bytes) {
    char* q = p;
    p += (bytes + 255) & ~(size_t)255;
    return q;
  };
  float* bufA    = (float*)alloc((size_t)N * 128 * 4);
  float* bufB    = (float*)alloc((size_t)N * 128 * 4);
  float* bufC    = (float*)alloc((size_t)N * 128 * 4);
  int*   cnt     = (int*)alloc((size_t)N * 4);
  int*   row_ptr = (int*)alloc((size_t)(N + 1) * 4);
  int*   cursor  = (int*)alloc((size_t)N * 4);
  int*   csr_src = (int*)alloc((size_t)E * 4);
  int*   bsum    = (int*)alloc(256 * 4);
  float* dinv    = (float*)alloc((size_t)N * 4);
  float* Wcat    = (float*)alloc(128 * 128 * 4);
  float* bcat    = (float*)alloc(128 * 4);
  (void)ws_size; (void)in_sizes; (void)n_in; (void)out_size;

  int nb = (N + 255) / 256;  // 196

  zero_int<<<(N + 255) / 256, 256, 0, stream>>>(cnt, N);
  count_deg<<<(E + 255) / 256, 256, 0, stream>>>(dst, cnt, E);
  block_sums<<<nb, 256, 0, stream>>>(cnt, bsum, N);
  scan_bsums<<<1, 64, 0, stream>>>(bsum, nb);
  scan_chunks<<<nb, 256, 0, stream>>>(cnt, bsum, row_ptr, cursor, N);
  compute_dinv<<<(N + 255) / 256, 256, 0, stream>>>(cnt, dinv, N);
  scatter_edges<<<(E + 255) / 256, 256, 0, stream>>>(src, dst, cursor, csr_src, E);
  make_wcat<<<(128 * 128 + 255) / 256, 256, 0, stream>>>(W_mean, W_logvar, b_mean, b_logvar, Wcat, bcat);

  int ggrid = (N + 1) / 2;  // 2 rows per block

  // layer 1a: f2h = tanh(P(feature @ W_f2h) + b)
  gemm128<128><<<ggrid, 256, 0, stream>>>(feature, W_f2h, bufA, N);
  prop128<<<N, 128, 0, stream>>>(bufA, bufB, row_ptr, csr_src, dinv, b_f2h, N, 1);
  // layer 1b: c2h = tanh(P(condition @ W_c2h) + b)
  gemm128<64><<<ggrid, 256, 0, stream>>>(condition, W_c2h, bufA, N);
  prop128<<<N, 128, 0, stream>>>(bufA, bufC, row_ptr, csr_src, dinv, b_c2h, N, 1);
  // layer 2: h = tanh(P([f2h|c2h] @ W_h2h) + b)
  gemm_cat<<<ggrid, 256, 0, stream>>>(bufB, bufC, W_h2h, bufA, N);
  prop128<<<N, 128, 0, stream>>>(bufA, bufB, row_ptr, csr_src, dinv, b_h2h, N, 1);
  // layer 3: [mean|logvar] = P(h @ [W_mean|W_logvar]) + [b_mean|b_logvar]
  gemm128<128><<<ggrid, 256, 0, stream>>>(bufB, Wcat, bufA, N);
  prop128<<<N, 128, 0, stream>>>(bufA, bufC, row_ptr, csr_src, dinv, bcat, N, 0);
  // epilogue
  finalize<<<(N * 64 + 255) / 256, 256, 0, stream>>>(bufC, noise, (float*)d_out, N);
}

// Round 2
// 617.636 us; speedup vs baseline: 1.4862x; 1.4862x over previous
//
#include <hip/hip_runtime.h>
#include <math.h>

namespace {

constexpr int N = 50000;
constexpr int E = 800000;

// ---------- CSR build ----------

__global__ void zero_int(int* p, int n) {
  int i = blockIdx.x * blockDim.x + threadIdx.x;
  if (i < n) p[i] = 0;
}

__global__ void count_deg(const int* __restrict__ dst, int* __restrict__ cnt, int e) {
  int i = blockIdx.x * blockDim.x + threadIdx.x;
  if (i < e) atomicAdd(&cnt[dst[i]], 1);
}

__global__ void block_sums(const int* __restrict__ cnt, int* __restrict__ bsum, int n) {
  int tid = threadIdx.x;
  int i = blockIdx.x * 256 + tid;
  int v = (i < n) ? cnt[i] : 0;
  for (int off = 32; off > 0; off >>= 1) v += __shfl_down(v, off, 64);
  __shared__ int sred[4];
  if ((tid & 63) == 0) sred[tid >> 6] = v;
  __syncthreads();
  if (tid == 0) bsum[blockIdx.x] = sred[0] + sred[1] + sred[2] + sred[3];
}

__global__ void scan_bsums(int* bsum, int nb) {
  if (threadIdx.x == 0 && blockIdx.x == 0) {
    int run = 0;
    for (int b = 0; b < nb; ++b) { int t = bsum[b]; bsum[b] = run; run += t; }
  }
}

__global__ void scan_chunks(const int* __restrict__ cnt, const int* __restrict__ bsum,
                            int* __restrict__ row_ptr, int* __restrict__ cursor, int n) {
  __shared__ int s[256];
  int tid = threadIdx.x;
  int i = blockIdx.x * 256 + tid;
  int v = (i < n) ? cnt[i] : 0;
  s[tid] = v;
  __syncthreads();
  for (int d = 1; d < 256; d <<= 1) {
    int t = (tid >= d) ? s[tid - d] : 0;
    __syncthreads();
    s[tid] += t;
    __syncthreads();
  }
  if (i < n) {
    int excl = bsum[blockIdx.x] + s[tid] - v;
    row_ptr[i] = excl;
    cursor[i] = excl;
    if (i == n - 1) row_ptr[n] = excl + v;
  }
}

__global__ void compute_dinv(const int* __restrict__ cnt, float* __restrict__ dinv, int n) {
  int i = blockIdx.x * blockDim.x + threadIdx.x;
  if (i < n) dinv[i] = rsqrtf((float)(cnt[i] + 1));
}

__global__ void scatter_edges(const int* __restrict__ src, const int* __restrict__ dst,
                              int* __restrict__ cursor, int* __restrict__ csr_src, int e) {
  int i = blockIdx.x * blockDim.x + threadIdx.x;
  if (i < e) {
    int d = dst[i];
    int pos = atomicAdd(&cursor[d], 1);
    csr_src[pos] = src[i];
  }
}

// ---------- weight concat for [W_mean | W_logvar] ----------

__global__ void make_wcat(const float* __restrict__ Wm, const float* __restrict__ Wl,
                          const float* __restrict__ bm, const float* __restrict__ bl,
                          float* __restrict__ Wcat, float* __restrict__ bcat) {
  int idx = blockIdx.x * blockDim.x + threadIdx.x;
  if (idx < 128 * 128) {
    int k = idx >> 7, j = idx & 127;
    Wcat[idx] = (j < 64) ? Wm[k * 64 + j] : Wl[k * 64 + (j - 64)];
  }
  if (idx < 64) bcat[idx] = bm[idx];
  else if (idx < 128) bcat[idx] = bl[idx - 64];
}

// ---------- tiled GEMM: C[n x 128] = A[n x K] @ W[K x 128] ----------
// 64 rows x 128 cols per 256-thread block; 8x4(f4) register tile per thread.
// CAT: K=256, A given as two N x 128 halves.

#define FMA4(ACC, AV, WV)                 \
  ACC.x = fmaf(AV, WV.x, ACC.x);          \
  ACC.y = fmaf(AV, WV.y, ACC.y);          \
  ACC.z = fmaf(AV, WV.z, ACC.z);          \
  ACC.w = fmaf(AV, WV.w, ACC.w);

template <int K, bool CAT>
__global__ __launch_bounds__(256) void gemm_tile(const float* __restrict__ A1,
                                                 const float* __restrict__ A2,
                                                 const float* __restrict__ W,
                                                 float* __restrict__ C, int n) {
  constexpr int KC = 64;          // K-chunk staged in LDS
  constexpr int LP = 68;          // padded LDS row stride (floats), 16B-aligned
  constexpr int SA = CAT ? 128 : K;  // global row stride of A source
  __shared__ float As[64 * LP];
  int tid = threadIdx.x;
  int r0 = blockIdx.x * 64;
  int lane = tid & 31;   // col group: cols lane*4 .. lane*4+3
  int rt = tid >> 5;     // row group: rows rt + 8*i
  const float4* W4 = (const float4*)W;

  float4 acc[8];
#pragma unroll
  for (int i = 0; i < 8; ++i) acc[i] = make_float4(0.f, 0.f, 0.f, 0.f);

  for (int k0 = 0; k0 < K; k0 += KC) {
    const float* Asrc = (CAT && k0 >= 128) ? A2 : A1;
    int kbase = CAT ? (k0 >= 128 ? k0 - 128 : k0) : k0;
    __syncthreads();
    // stage 64 rows x 64 ks = 1024 float4, 4 per thread, coalesced
#pragma unroll
    for (int l = 0; l < 4; ++l) {
      int f = l * 256 + tid;   // float4 index in chunk
      int row = f >> 4;        // 16 float4 per row
      int k4 = f & 15;
      int gr = r0 + row;
      float4 v = make_float4(0.f, 0.f, 0.f, 0.f);
      if (gr < n) v = *(const float4*)(Asrc + (long)gr * SA + kbase + k4 * 4);
      *(float4*)(As + row * LP + k4 * 4) = v;
    }
    __syncthreads();
#pragma unroll
    for (int kk = 0; kk < KC / 4; ++kk) {
      float4 w0 = W4[(size_t)(k0 + kk * 4 + 0) * 32 + lane];
      float4 w1 = W4[(size_t)(k0 + kk * 4 + 1) * 32 + lane];
      float4 w2 = W4[(size_t)(k0 + kk * 4 + 2) * 32 + lane];
      float4 w3 = W4[(size_t)(k0 + kk * 4 + 3) * 32 + lane];
#pragma unroll
      for (int i = 0; i < 8; ++i) {
        int r = rt + 8 * i;
        float4 a = *(const float4*)(As + r * LP + kk * 4);
        FMA4(acc[i], a.x, w0);
        FMA4(acc[i], a.y, w1);
        FMA4(acc[i], a.z, w2);
        FMA4(acc[i], a.w, w3);
      }
    }
  }
#pragma unroll
  for (int i = 0; i < 8; ++i) {
    int r = r0 + rt + 8 * i;
    if (r < n) *(float4*)(C + (long)r * 128 + lane * 4) = acc[i];
  }
}

// ---------- propagation: Y[i] = act( dinv[i]*(sum_in dinv[s]*X[s] + dinv[i]*X[i]) + b ) ----------
// 32 lanes x float4 per row, 8 rows per 256-thread block.

__global__ __launch_bounds__(256) void prop_f4(const float4* __restrict__ X4,
                                               float4* __restrict__ Y4,
                                               const int* __restrict__ row_ptr,
                                               const int* __restrict__ csr_src,
                                               const float* __restrict__ dinv,
                                               const float4* __restrict__ bias4,
                                               int n, int act) {
  int lane = threadIdx.x & 31;
  int rloc = threadIdx.x >> 5;
  int i = blockIdx.x * 8 + rloc;
  if (i >= n) return;
  float di = dinv[i];
  float4 x = X4[(size_t)i * 32 + lane];
  float4 acc = make_float4(di * x.x, di * x.y, di * x.z, di * x.w);
  int e0 = row_ptr[i], e1 = row_ptr[i + 1];
  for (int e = e0; e < e1; ++e) {
    int s = csr_src[e];
    float dv = dinv[s];
    float4 xs = X4[(size_t)s * 32 + lane];
    acc.x = fmaf(dv, xs.x, acc.x);
    acc.y = fmaf(dv, xs.y, acc.y);
    acc.z = fmaf(dv, xs.z, acc.z);
    acc.w = fmaf(dv, xs.w, acc.w);
  }
  float4 b = bias4[lane];
  float4 v = make_float4(fmaf(di, acc.x, b.x), fmaf(di, acc.y, b.y),
                         fmaf(di, acc.z, b.z), fmaf(di, acc.w, b.w));
  if (act) {
    v.x = tanhf(v.x); v.y = tanhf(v.y); v.z = tanhf(v.z); v.w = tanhf(v.w);
  }
  Y4[(size_t)i * 32 + lane] = v;
}

// ---------- epilogue: z = noise*exp(0.5*logvar)+mean; out = [z | mean | logvar] ----------

__global__ void finalize(const float* __restrict__ ML, const float* __restrict__ noise,
                         float* __restrict__ out, int n) {
  int idx = blockIdx.x * blockDim.x + threadIdx.x;
  if (idx >= n * 64) return;
  int i = idx >> 6, j = idx & 63;
  float mean = ML[(long)i * 128 + j];
  float logvar = ML[(long)i * 128 + 64 + j];
  float z = fmaf(noise[idx], expf(0.5f * logvar), mean);
  out[idx] = z;
  out[(long)n * 64 + idx] = mean;
  out[(long)2 * n * 64 + idx] = logvar;
}

}  // namespace

extern "C" void kernel_launch(void* const* d_in, const int* in_sizes, int n_in,
                              void* d_out, int out_size, void* d_ws, size_t ws_size,
                              hipStream_t stream) {
  const float* feature   = (const float*)d_in[0];
  const float* condition = (const float*)d_in[1];
  const int*   ei        = (const int*)d_in[2];
  const float* noise     = (const float*)d_in[3];
  const float* W_f2h     = (const float*)d_in[4];
  const float* b_f2h     = (const float*)d_in[5];
  const float* W_c2h     = (const float*)d_in[6];
  const float* b_c2h     = (const float*)d_in[7];
  const float* W_h2h     = (const float*)d_in[8];
  const float* b_h2h     = (const float*)d_in[9];
  const float* W_mean    = (const float*)d_in[10];
  const float* b_mean    = (const float*)d_in[11];
  const float* W_logvar  = (const float*)d_in[12];
  const float* b_logvar  = (const float*)d_in[13];

  const int* src = ei;        // edge_index[0]
  const int* dst = ei + E;    // edge_index[1]

  char* p = (char*)d_ws;
  auto alloc = [&](size_t bytes) {
    char* q = p;
    p += (bytes + 255) & ~(size_t)255;
    return q;
  };
  float* bufA    = (float*)alloc((size_t)N * 128 * 4);
  float* bufB    = (float*)alloc((size_t)N * 128 * 4);
  float* bufC    = (float*)alloc((size_t)N * 128 * 4);
  int*   cnt     = (int*)alloc((size_t)N * 4);
  int*   row_ptr = (int*)alloc((size_t)(N + 1) * 4);
  int*   cursor  = (int*)alloc((size_t)N * 4);
  int*   csr_src = (int*)alloc((size_t)E * 4);
  int*   bsum    = (int*)alloc(256 * 4);
  float* dinv    = (float*)alloc((size_t)N * 4);
  float* Wcat    = (float*)alloc(128 * 128 * 4);
  float* bcat    = (float*)alloc(128 * 4);
  (void)ws_size; (void)in_sizes; (void)n_in; (void)out_size;

  int nb = (N + 255) / 256;  // 196

  zero_int<<<(N + 255) / 256, 256, 0, stream>>>(cnt, N);
  count_deg<<<(E + 255) / 256, 256, 0, stream>>>(dst, cnt, E);
  block_sums<<<nb, 256, 0, stream>>>(cnt, bsum, N);
  scan_bsums<<<1, 64, 0, stream>>>(bsum, nb);
  scan_chunks<<<nb, 256, 0, stream>>>(cnt, bsum, row_ptr, cursor, N);
  compute_dinv<<<(N + 255) / 256, 256, 0, stream>>>(cnt, dinv, N);
  scatter_edges<<<(E + 255) / 256, 256, 0, stream>>>(src, dst, cursor, csr_src, E);
  make_wcat<<<(128 * 128 + 255) / 256, 256, 0, stream>>>(W_mean, W_logvar, b_mean, b_logvar, Wcat, bcat);

  int ggrid = (N + 63) / 64;   // 782
  int pgrid = (N + 7) / 8;     // 6250

  // layer 1a: f2h = tanh(P(feature @ W_f2h) + b)
  gemm_tile<128, false><<<ggrid, 256, 0, stream>>>(feature, nullptr, W_f2h, bufA, N);
  prop_f4<<<pgrid, 256, 0, stream>>>((const float4*)bufA, (float4*)bufB, row_ptr, csr_src, dinv,
                                     (const float4*)b_f2h, N, 1);
  // layer 1b: c2h = tanh(P(condition @ W_c2h) + b)
  gemm_tile<64, false><<<ggrid, 256, 0, stream>>>(condition, nullptr, W_c2h, bufA, N);
  prop_f4<<<pgrid, 256, 0, stream>>>((const float4*)bufA, (float4*)bufC, row_ptr, csr_src, dinv,
                                     (const float4*)b_c2h, N, 1);
  // layer 2: h = tanh(P([f2h|c2h] @ W_h2h) + b)
  gemm_tile<256, true><<<ggrid, 256, 0, stream>>>(bufB, bufC, W_h2h, bufA, N);
  prop_f4<<<pgrid, 256, 0, stream>>>((const float4*)bufA, (float4*)bufB, row_ptr, csr_src, dinv,
                                     (const float4*)b_h2h, N, 1);
  // layer 3: [mean|logvar] = P(h @ [W_mean|W_logvar]) + [b_mean|b_logvar]
  gemm_tile<128, false><<<ggrid, 256, 0, stream>>>(bufB, nullptr, Wcat, bufA, N);
  prop_f4<<<pgrid, 256, 0, stream>>>((const float4*)bufA, (float4*)bufC, row_ptr, csr_src, dinv,
                                     (const float4*)bcat, N, 0);
  // epilogue
  finalize<<<(N * 64 + 255) / 256, 256, 0, stream>>>(bufC, noise, (float*)d_out, N);
}

// Round 3
// 535.045 us; speedup vs baseline: 1.7156x; 1.1544x over previous
//
#include <hip/hip_runtime.h>
#include <math.h>

namespace {

constexpr int N = 50000;
constexpr int E = 800000;

// ---------- CSR build ----------

__global__ void zero_int(int* p, int n) {
  int i = blockIdx.x * blockDim.x + threadIdx.x;
  if (i < n) p[i] = 0;
}

__global__ void count_deg(const int* __restrict__ dst, int* __restrict__ cnt, int e) {
  int i = blockIdx.x * blockDim.x + threadIdx.x;
  if (i < e) atomicAdd(&cnt[dst[i]], 1);
}

__global__ void block_sums(const int* __restrict__ cnt, int* __restrict__ bsum, int n) {
  int tid = threadIdx.x;
  int i = blockIdx.x * 256 + tid;
  int v = (i < n) ? cnt[i] : 0;
  for (int off = 32; off > 0; off >>= 1) v += __shfl_down(v, off, 64);
  __shared__ int sred[4];
  if ((tid & 63) == 0) sred[tid >> 6] = v;
  __syncthreads();
  if (tid == 0) bsum[blockIdx.x] = sred[0] + sred[1] + sred[2] + sred[3];
}

__global__ void scan_bsums(int* bsum, int nb) {
  if (threadIdx.x == 0 && blockIdx.x == 0) {
    int run = 0;
    for (int b = 0; b < nb; ++b) { int t = bsum[b]; bsum[b] = run; run += t; }
  }
}

__global__ void scan_chunks(const int* __restrict__ cnt, const int* __restrict__ bsum,
                            int* __restrict__ row_ptr, int* __restrict__ cursor, int n) {
  __shared__ int s[256];
  int tid = threadIdx.x;
  int i = blockIdx.x * 256 + tid;
  int v = (i < n) ? cnt[i] : 0;
  s[tid] = v;
  __syncthreads();
  for (int d = 1; d < 256; d <<= 1) {
    int t = (tid >= d) ? s[tid - d] : 0;
    __syncthreads();
    s[tid] += t;
    __syncthreads();
  }
  if (i < n) {
    int excl = bsum[blockIdx.x] + s[tid] - v;
    row_ptr[i] = excl;
    cursor[i] = excl;
    if (i == n - 1) row_ptr[n] = excl + v;
  }
}

__global__ void compute_dinv(const int* __restrict__ cnt, float* __restrict__ dinv, int n) {
  int i = blockIdx.x * blockDim.x + threadIdx.x;
  if (i < n) dinv[i] = rsqrtf((float)(cnt[i] + 1));
}

__global__ void scatter_edges(const int* __restrict__ src, const int* __restrict__ dst,
                              int* __restrict__ cursor, int* __restrict__ csr_src, int e) {
  int i = blockIdx.x * blockDim.x + threadIdx.x;
  if (i < e) {
    int d = dst[i];
    int pos = atomicAdd(&cursor[d], 1);
    csr_src[pos] = src[i];
  }
}

// ---------- weight concat for [W_mean | W_logvar] ----------

__global__ void make_wcat(const float* __restrict__ Wm, const float* __restrict__ Wl,
                          const float* __restrict__ bm, const float* __restrict__ bl,
                          float* __restrict__ Wcat, float* __restrict__ bcat) {
  int idx = blockIdx.x * blockDim.x + threadIdx.x;
  if (idx < 128 * 128) {
    int k = idx >> 7, j = idx & 127;
    Wcat[idx] = (j < 64) ? Wm[k * 64 + j] : Wl[k * 64 + (j - 64)];
  }
  if (idx < 64) bcat[idx] = bm[idx];
  else if (idx < 128) bcat[idx] = bl[idx - 64];
}

// ---------- tiled GEMM: C[n x 128] = A[n x K] @ W[K x 128] ----------
// 64 rows x 128 cols per 256-thread block; 8x4(f4) register tile per thread.
// CAT: K=256, A given as two N x 128 halves.
// NOTE: k0/kk loops are pinned to unroll 1 — full unroll previously hoisted
// all W loads, hit 256 VGPRs and spilled 198 MB of scratch per dispatch.

#define FMA4(ACC, AV, WV)                 \
  ACC.x = fmaf(AV, WV.x, ACC.x);          \
  ACC.y = fmaf(AV, WV.y, ACC.y);          \
  ACC.z = fmaf(AV, WV.z, ACC.z);          \
  ACC.w = fmaf(AV, WV.w, ACC.w);

template <int K, bool CAT>
__global__ __launch_bounds__(256) void gemm_tile(const float* __restrict__ A1,
                                                 const float* __restrict__ A2,
                                                 const float* __restrict__ W,
                                                 float* __restrict__ C, int n) {
  constexpr int KC = 64;          // K-chunk staged in LDS
  constexpr int LP = 68;          // padded LDS row stride (floats), 16B-aligned
  constexpr int SA = CAT ? 128 : K;  // global row stride of A source
  __shared__ float As[64 * LP];
  int tid = threadIdx.x;
  int r0 = blockIdx.x * 64;
  int lane = tid & 31;   // col group: cols lane*4 .. lane*4+3
  int rt = tid >> 5;     // row group: rows rt + 8*i
  const float4* W4 = (const float4*)W;

  float4 acc[8];
#pragma unroll
  for (int i = 0; i < 8; ++i) acc[i] = make_float4(0.f, 0.f, 0.f, 0.f);

#pragma unroll 1
  for (int k0 = 0; k0 < K; k0 += KC) {
    const float* Asrc = (CAT && k0 >= 128) ? A2 : A1;
    int kbase = CAT ? (k0 >= 128 ? k0 - 128 : k0) : k0;
    __syncthreads();
    // stage 64 rows x 64 ks = 1024 float4, 4 per thread, coalesced
#pragma unroll
    for (int l = 0; l < 4; ++l) {
      int f = l * 256 + tid;   // float4 index in chunk
      int row = f >> 4;        // 16 float4 per row
      int k4 = f & 15;
      int gr = r0 + row;
      float4 v = make_float4(0.f, 0.f, 0.f, 0.f);
      if (gr < n) v = *(const float4*)(Asrc + (long)gr * SA + kbase + k4 * 4);
      *(float4*)(As + row * LP + k4 * 4) = v;
    }
    __syncthreads();
#pragma unroll 1
    for (int kk = 0; kk < KC / 4; ++kk) {
      float4 w0 = W4[(size_t)(k0 + kk * 4 + 0) * 32 + lane];
      float4 w1 = W4[(size_t)(k0 + kk * 4 + 1) * 32 + lane];
      float4 w2 = W4[(size_t)(k0 + kk * 4 + 2) * 32 + lane];
      float4 w3 = W4[(size_t)(k0 + kk * 4 + 3) * 32 + lane];
#pragma unroll
      for (int i = 0; i < 8; ++i) {
        int r = rt + 8 * i;
        float4 a = *(const float4*)(As + r * LP + kk * 4);
        FMA4(acc[i], a.x, w0);
        FMA4(acc[i], a.y, w1);
        FMA4(acc[i], a.z, w2);
        FMA4(acc[i], a.w, w3);
      }
    }
  }
#pragma unroll
  for (int i = 0; i < 8; ++i) {
    int r = r0 + rt + 8 * i;
    if (r < n) *(float4*)(C + (long)r * 128 + lane * 4) = acc[i];
  }
}

// ---------- propagation: Y[i] = act( dinv[i]*(sum_in dinv[s]*X[s] + dinv[i]*X[i]) + b ) ----------
// 32 lanes x float4 per row, 8 rows per 256-thread block.

__global__ __launch_bounds__(256) void prop_f4(const float4* __restrict__ X4,
                                               float4* __restrict__ Y4,
                                               const int* __restrict__ row_ptr,
                                               const int* __restrict__ csr_src,
                                               const float* __restrict__ dinv,
                                               const float4* __restrict__ bias4,
                                               int n, int act) {
  int lane = threadIdx.x & 31;
  int rloc = threadIdx.x >> 5;
  int i = blockIdx.x * 8 + rloc;
  if (i >= n) return;
  float di = dinv[i];
  float4 x = X4[(size_t)i * 32 + lane];
  float4 acc = make_float4(di * x.x, di * x.y, di * x.z, di * x.w);
  int e0 = row_ptr[i], e1 = row_ptr[i + 1];
  for (int e = e0; e < e1; ++e) {
    int s = csr_src[e];
    float dv = dinv[s];
    float4 xs = X4[(size_t)s * 32 + lane];
    acc.x = fmaf(dv, xs.x, acc.x);
    acc.y = fmaf(dv, xs.y, acc.y);
    acc.z = fmaf(dv, xs.z, acc.z);
    acc.w = fmaf(dv, xs.w, acc.w);
  }
  float4 b = bias4[lane];
  float4 v = make_float4(fmaf(di, acc.x, b.x), fmaf(di, acc.y, b.y),
                         fmaf(di, acc.z, b.z), fmaf(di, acc.w, b.w));
  if (act) {
    v.x = tanhf(v.x); v.y = tanhf(v.y); v.z = tanhf(v.z); v.w = tanhf(v.w);
  }
  Y4[(size_t)i * 32 + lane] = v;
}

// ---------- epilogue: z = noise*exp(0.5*logvar)+mean; out = [z | mean | logvar] ----------

__global__ void finalize(const float* __restrict__ ML, const float* __restrict__ noise,
                         float* __restrict__ out, int n) {
  int idx = blockIdx.x * blockDim.x + threadIdx.x;
  if (idx >= n * 64) return;
  int i = idx >> 6, j = idx & 63;
  float mean = ML[(long)i * 128 + j];
  float logvar = ML[(long)i * 128 + 64 + j];
  float z = fmaf(noise[idx], expf(0.5f * logvar), mean);
  out[idx] = z;
  out[(long)n * 64 + idx] = mean;
  out[(long)2 * n * 64 + idx] = logvar;
}

}  // namespace

extern "C" void kernel_launch(void* const* d_in, const int* in_sizes, int n_in,
                              void* d_out, int out_size, void* d_ws, size_t ws_size,
                              hipStream_t stream) {
  const float* feature   = (const float*)d_in[0];
  const float* condition = (const float*)d_in[1];
  const int*   ei        = (const int*)d_in[2];
  const float* noise     = (const float*)d_in[3];
  const float* W_f2h     = (const float*)d_in[4];
  const float* b_f2h     = (const float*)d_in[5];
  const float* W_c2h     = (const float*)d_in[6];
  const float* b_c2h     = (const float*)d_in[7];
  const float* W_h2h     = (const float*)d_in[8];
  const float* b_h2h     = (const float*)d_in[9];
  const float* W_mean    = (const float*)d_in[10];
  const float* b_mean    = (const float*)d_in[11];
  const float* W_logvar  = (const float*)d_in[12];
  const float* b_logvar  = (const float*)d_in[13];

  const int* src = ei;        // edge_index[0]
  const int* dst = ei + E;    // edge_index[1]

  char* p = (char*)d_ws;
  auto alloc = [&](size_t bytes) {
    char* q = p;
    p += (bytes + 255) & ~(size_t)255;
    return q;
  };
  float* bufA    = (float*)alloc((size_t)N * 128 * 4);
  float* bufB    = (float*)alloc((size_t)N * 128 * 4);
  float* bufC    = (float*)alloc((size_t)N * 128 * 4);
  int*   cnt     = (int*)alloc((size_t)N * 4);
  int*   row_ptr = (int*)alloc((size_t)(N + 1) * 4);
  int*   cursor  = (int*)alloc((size_t)N * 4);
  int*   csr_src = (int*)alloc((size_t)E * 4);
  int*   bsum    = (int*)alloc(256 * 4);
  float* dinv    = (float*)alloc((size_t)N * 4);
  float* Wcat    = (float*)alloc(128 * 128 * 4);
  float* bcat    = (float*)alloc(128 * 4);
  (void)ws_size; (void)in_sizes; (void)n_in; (void)out_size;

  int nb = (N + 255) / 256;  // 196

  zero_int<<<(N + 255) / 256, 256, 0, stream>>>(cnt, N);
  count_deg<<<(E + 255) / 256, 256, 0, stream>>>(dst, cnt, E);
  block_sums<<<nb, 256, 0, stream>>>(cnt, bsum, N);
  scan_bsums<<<1, 64, 0, stream>>>(bsum, nb);
  scan_chunks<<<nb, 256, 0, stream>>>(cnt, bsum, row_ptr, cursor, N);
  compute_dinv<<<(N + 255) / 256, 256, 0, stream>>>(cnt, dinv, N);
  scatter_edges<<<(E + 255) / 256, 256, 0, stream>>>(src, dst, cursor, csr_src, E);
  make_wcat<<<(128 * 128 + 255) / 256, 256, 0, stream>>>(W_mean, W_logvar, b_mean, b_logvar, Wcat, bcat);

  int ggrid = (N + 63) / 64;   // 782
  int pgrid = (N + 7) / 8;     // 6250

  // layer 1a: f2h = tanh(P(feature @ W_f2h) + b)
  gemm_tile<128, false><<<ggrid, 256, 0, stream>>>(feature, nullptr, W_f2h, bufA, N);
  prop_f4<<<pgrid, 256, 0, stream>>>((const float4*)bufA, (float4*)bufB, row_ptr, csr_src, dinv,
                                     (const float4*)b_f2h, N, 1);
  // layer 1b: c2h = tanh(P(condition @ W_c2h) + b)
  gemm_tile<64, false><<<ggrid, 256, 0, stream>>>(condition, nullptr, W_c2h, bufA, N);
  prop_f4<<<pgrid, 256, 0, stream>>>((const float4*)bufA, (float4*)bufC, row_ptr, csr_src, dinv,
                                     (const float4*)b_c2h, N, 1);
  // layer 2: h = tanh(P([f2h|c2h] @ W_h2h) + b)
  gemm_tile<256, true><<<ggrid, 256, 0, stream>>>(bufB, bufC, W_h2h, bufA, N);
  prop_f4<<<pgrid, 256, 0, stream>>>((const float4*)bufA, (float4*)bufB, row_ptr, csr_src, dinv,
                                     (const float4*)b_h2h, N, 1);
  // layer 3: [mean|logvar] = P(h @ [W_mean|W_logvar]) + [b_mean|b_logvar]
  gemm_tile<128, false><<<ggrid, 256, 0, stream>>>(bufB, nullptr, Wcat, bufA, N);
  prop_f4<<<pgrid, 256, 0, stream>>>((const float4*)bufA, (float4*)bufC, row_ptr, csr_src, dinv,
                                     (const float4*)bcat, N, 0);
  // epilogue
  finalize<<<(N * 64 + 255) / 256, 256, 0, stream>>>(bufC, noise, (float*)d_out, N);
}

// Round 4
// 460.391 us; speedup vs baseline: 1.9938x; 1.1622x over previous
//
#include <hip/hip_runtime.h>
#include <math.h>

namespace {

constexpr int N = 50000;
constexpr int E = 800000;

// ---------- bf16 helpers (RTNE, no NaN handling needed for finite data) ----------

__device__ inline unsigned short f2bf(float f) {
  unsigned int b = __float_as_uint(f);
  unsigned int r = (b + 0x7fffu + ((b >> 16) & 1u)) >> 16;
  return (unsigned short)r;
}
__device__ inline float bf_lo(unsigned int u) { return __uint_as_float(u << 16); }
__device__ inline float bf_hi(unsigned int u) { return __uint_as_float(u & 0xffff0000u); }

// ---------- CSR build ----------

__global__ void zero_int(int* p, int n) {
  int i = blockIdx.x * blockDim.x + threadIdx.x;
  if (i < n) p[i] = 0;
}

__global__ void count_deg(const int* __restrict__ dst, int* __restrict__ cnt, int e) {
  int i = blockIdx.x * blockDim.x + threadIdx.x;
  if (i < e) atomicAdd(&cnt[dst[i]], 1);
}

__global__ void block_sums(const int* __restrict__ cnt, int* __restrict__ bsum, int n) {
  int tid = threadIdx.x;
  int i = blockIdx.x * 256 + tid;
  int v = (i < n) ? cnt[i] : 0;
  for (int off = 32; off > 0; off >>= 1) v += __shfl_down(v, off, 64);
  __shared__ int sred[4];
  if ((tid & 63) == 0) sred[tid >> 6] = v;
  __syncthreads();
  if (tid == 0) bsum[blockIdx.x] = sred[0] + sred[1] + sred[2] + sred[3];
}

__global__ void scan_bsums(int* bsum, int nb) {
  if (threadIdx.x == 0 && blockIdx.x == 0) {
    int run = 0;
    for (int b = 0; b < nb; ++b) { int t = bsum[b]; bsum[b] = run; run += t; }
  }
}

__global__ void scan_chunks(const int* __restrict__ cnt, const int* __restrict__ bsum,
                            int* __restrict__ row_ptr, int* __restrict__ cursor, int n) {
  __shared__ int s[256];
  int tid = threadIdx.x;
  int i = blockIdx.x * 256 + tid;
  int v = (i < n) ? cnt[i] : 0;
  s[tid] = v;
  __syncthreads();
  for (int d = 1; d < 256; d <<= 1) {
    int t = (tid >= d) ? s[tid - d] : 0;
    __syncthreads();
    s[tid] += t;
    __syncthreads();
  }
  if (i < n) {
    int excl = bsum[blockIdx.x] + s[tid] - v;
    row_ptr[i] = excl;
    cursor[i] = excl;
    if (i == n - 1) row_ptr[n] = excl + v;
  }
}

__global__ void compute_dinv(const int* __restrict__ cnt, float* __restrict__ dinv, int n) {
  int i = blockIdx.x * blockDim.x + threadIdx.x;
  if (i < n) dinv[i] = rsqrtf((float)(cnt[i] + 1));
}

__global__ void scatter_edges(const int* __restrict__ src, const int* __restrict__ dst,
                              int* __restrict__ cursor, int* __restrict__ csr_src, int e) {
  int i = blockIdx.x * blockDim.x + threadIdx.x;
  if (i < e) {
    int d = dst[i];
    int pos = atomicAdd(&cursor[d], 1);
    csr_src[pos] = src[i];
  }
}

// ---------- weight concat + condition cvt ----------

__global__ void make_wcat(const float* __restrict__ Wm, const float* __restrict__ Wl,
                          const float* __restrict__ bm, const float* __restrict__ bl,
                          float* __restrict__ Wcat, float* __restrict__ bcat) {
  int idx = blockIdx.x * blockDim.x + threadIdx.x;
  if (idx < 128 * 128) {
    int k = idx >> 7, j = idx & 127;
    Wcat[idx] = (j < 64) ? Wm[k * 64 + j] : Wl[k * 64 + (j - 64)];
  }
  if (idx < 64) bcat[idx] = bm[idx];
  else if (idx < 128) bcat[idx] = bl[idx - 64];
}

__global__ void cvt_bf(const float4* __restrict__ in, ushort4* __restrict__ out, int n4) {
  int t = blockIdx.x * blockDim.x + threadIdx.x;
  if (t >= n4) return;
  float4 v = in[t];
  ushort4 o;
  o.x = f2bf(v.x); o.y = f2bf(v.y); o.z = f2bf(v.z); o.w = f2bf(v.w);
  out[t] = o;
}

// ---------- tiled GEMM: C[n x 128] = A[n x K] @ W[K x 128] ----------
// 64 rows x 128 cols per 256-thread block; 8x4(f4) register tile per thread.
// EPI: 0 = plain fp32, 1 = tanh(acc+bias) fp32, 2 = bf16 store (no bias).
// k0/kk loops pinned to unroll 1 (full unroll spilled: 256 VGPR, 198MB scratch).

#define FMA4(ACC, AV, WV)                 \
  ACC.x = fmaf(AV, WV.x, ACC.x);          \
  ACC.y = fmaf(AV, WV.y, ACC.y);          \
  ACC.z = fmaf(AV, WV.z, ACC.z);          \
  ACC.w = fmaf(AV, WV.w, ACC.w);

template <int K, bool CAT, int EPI>
__global__ __launch_bounds__(256) void gemm_tile(const float* __restrict__ A1,
                                                 const float* __restrict__ A2,
                                                 const float* __restrict__ W,
                                                 const float* __restrict__ bias,
                                                 void* __restrict__ Cout, int n) {
  constexpr int KC = 64;
  constexpr int LP = 68;
  constexpr int SA = CAT ? 128 : K;
  __shared__ float As[64 * LP];
  int tid = threadIdx.x;
  int r0 = blockIdx.x * 64;
  int lane = tid & 31;
  int rt = tid >> 5;
  const float4* W4 = (const float4*)W;

  float4 acc[8];
#pragma unroll
  for (int i = 0; i < 8; ++i) acc[i] = make_float4(0.f, 0.f, 0.f, 0.f);

#pragma unroll 1
  for (int k0 = 0; k0 < K; k0 += KC) {
    const float* Asrc = (CAT && k0 >= 128) ? A2 : A1;
    int kbase = CAT ? (k0 >= 128 ? k0 - 128 : k0) : k0;
    __syncthreads();
#pragma unroll
    for (int l = 0; l < 4; ++l) {
      int f = l * 256 + tid;
      int row = f >> 4;
      int k4 = f & 15;
      int gr = r0 + row;
      float4 v = make_float4(0.f, 0.f, 0.f, 0.f);
      if (gr < n) v = *(const float4*)(Asrc + (long)gr * SA + kbase + k4 * 4);
      *(float4*)(As + row * LP + k4 * 4) = v;
    }
    __syncthreads();
#pragma unroll 1
    for (int kk = 0; kk < KC / 4; ++kk) {
      float4 w0 = W4[(size_t)(k0 + kk * 4 + 0) * 32 + lane];
      float4 w1 = W4[(size_t)(k0 + kk * 4 + 1) * 32 + lane];
      float4 w2 = W4[(size_t)(k0 + kk * 4 + 2) * 32 + lane];
      float4 w3 = W4[(size_t)(k0 + kk * 4 + 3) * 32 + lane];
#pragma unroll
      for (int i = 0; i < 8; ++i) {
        int r = rt + 8 * i;
        float4 a = *(const float4*)(As + r * LP + kk * 4);
        FMA4(acc[i], a.x, w0);
        FMA4(acc[i], a.y, w1);
        FMA4(acc[i], a.z, w2);
        FMA4(acc[i], a.w, w3);
      }
    }
  }
  float4 b4 = make_float4(0.f, 0.f, 0.f, 0.f);
  if (EPI == 1) b4 = *(const float4*)(bias + lane * 4);
#pragma unroll
  for (int i = 0; i < 8; ++i) {
    int r = r0 + rt + 8 * i;
    if (r >= n) continue;
    if (EPI == 0) {
      *(float4*)((float*)Cout + (long)r * 128 + lane * 4) = acc[i];
    } else if (EPI == 1) {
      float4 v = make_float4(tanhf(acc[i].x + b4.x), tanhf(acc[i].y + b4.y),
                             tanhf(acc[i].z + b4.z), tanhf(acc[i].w + b4.w));
      *(float4*)((float*)Cout + (long)r * 128 + lane * 4) = v;
    } else {
      ushort4 o;
      o.x = f2bf(acc[i].x); o.y = f2bf(acc[i].y);
      o.z = f2bf(acc[i].z); o.w = f2bf(acc[i].w);
      *(ushort4*)((unsigned short*)Cout + (long)r * 128 + lane * 4) = o;
    }
  }
}

// ---------- bf16 propagation: Y[i] = act( dinv[i]*(sum dinv[s]*X[s] + dinv[i]*X[i]) + b ) ----------
// COLS/8 lanes per row, each lane owns 8 bf16 cols (one uint4 load per gathered row).

template <int COLS, int ACT>
__global__ __launch_bounds__(256) void prop_bf(const unsigned short* __restrict__ X,
                                               float* __restrict__ Y,
                                               const int* __restrict__ row_ptr,
                                               const int* __restrict__ csr_src,
                                               const float* __restrict__ dinv,
                                               const float* __restrict__ bias, int n) {
  constexpr int LANES = COLS / 8;
  constexpr int RPB = 256 / LANES;
  int lane = threadIdx.x % LANES;
  int rloc = threadIdx.x / LANES;
  int i = blockIdx.x * RPB + rloc;
  if (i >= n) return;
  const uint4* X4 = (const uint4*)X;  // 8 bf16 per uint4, COLS/8 per row
  float di = dinv[i];
  float acc[8];
  {
    uint4 u = X4[(size_t)i * LANES + lane];
    acc[0] = di * bf_lo(u.x); acc[1] = di * bf_hi(u.x);
    acc[2] = di * bf_lo(u.y); acc[3] = di * bf_hi(u.y);
    acc[4] = di * bf_lo(u.z); acc[5] = di * bf_hi(u.z);
    acc[6] = di * bf_lo(u.w); acc[7] = di * bf_hi(u.w);
  }
  int e0 = row_ptr[i], e1 = row_ptr[i + 1];
  for (int e = e0; e < e1; ++e) {
    int s = csr_src[e];
    float dv = dinv[s];
    uint4 u = X4[(size_t)s * LANES + lane];
    acc[0] = fmaf(dv, bf_lo(u.x), acc[0]); acc[1] = fmaf(dv, bf_hi(u.x), acc[1]);
    acc[2] = fmaf(dv, bf_lo(u.y), acc[2]); acc[3] = fmaf(dv, bf_hi(u.y), acc[3]);
    acc[4] = fmaf(dv, bf_lo(u.z), acc[4]); acc[5] = fmaf(dv, bf_hi(u.z), acc[5]);
    acc[6] = fmaf(dv, bf_lo(u.w), acc[6]); acc[7] = fmaf(dv, bf_hi(u.w), acc[7]);
  }
  float out[8];
  if (ACT) {
#pragma unroll
    for (int j = 0; j < 8; ++j) out[j] = tanhf(fmaf(di, acc[j], bias[lane * 8 + j]));
  } else {
#pragma unroll
    for (int j = 0; j < 8; ++j) out[j] = di * acc[j];
  }
  float* yp = Y + (size_t)i * COLS + lane * 8;
  *(float4*)yp = make_float4(out[0], out[1], out[2], out[3]);
  *(float4*)(yp + 4) = make_float4(out[4], out[5], out[6], out[7]);
}

// ---------- final prop (fp32 gather, 32 lanes/row) with fused reparam epilogue ----------
// v[N x 128] = h@Wcat; out rows: [z | mean | logvar], z = noise*exp(0.5*logvar)+mean.

__global__ __launch_bounds__(256) void prop_fin(const float4* __restrict__ X4,
                                                const int* __restrict__ row_ptr,
                                                const int* __restrict__ csr_src,
                                                const float* __restrict__ dinv,
                                                const float4* __restrict__ bias4,
                                                const float4* __restrict__ noise4,
                                                float* __restrict__ out, int n) {
  int lane = threadIdx.x & 31;
  int rloc = threadIdx.x >> 5;
  int i = blockIdx.x * 8 + rloc;
  if (i >= n) return;
  float di = dinv[i];
  float4 x = X4[(size_t)i * 32 + lane];
  float4 acc = make_float4(di * x.x, di * x.y, di * x.z, di * x.w);
  int e0 = row_ptr[i], e1 = row_ptr[i + 1];
  for (int e = e0; e < e1; ++e) {
    int s = csr_src[e];
    float dv = dinv[s];
    float4 xs = X4[(size_t)s * 32 + lane];
    acc.x = fmaf(dv, xs.x, acc.x);
    acc.y = fmaf(dv, xs.y, acc.y);
    acc.z = fmaf(dv, xs.z, acc.z);
    acc.w = fmaf(dv, xs.w, acc.w);
  }
  float4 b = bias4[lane];
  float4 v = make_float4(fmaf(di, acc.x, b.x), fmaf(di, acc.y, b.y),
                         fmaf(di, acc.z, b.z), fmaf(di, acc.w, b.w));
  // lanes 0-15 hold mean cols (0-63), lanes 16-31 hold logvar cols (64-127)
  float4 p;  // partner values
  p.x = __shfl_xor(v.x, 16);
  p.y = __shfl_xor(v.y, 16);
  p.z = __shfl_xor(v.z, 16);
  p.w = __shfl_xor(v.w, 16);
  float4* out4 = (float4*)out;
  size_t n16 = (size_t)n * 16;
  if (lane < 16) {
    float4 nz = noise4[(size_t)i * 16 + lane];
    float4 z = make_float4(fmaf(nz.x, expf(0.5f * p.x), v.x),
                           fmaf(nz.y, expf(0.5f * p.y), v.y),
                           fmaf(nz.z, expf(0.5f * p.z), v.z),
                           fmaf(nz.w, expf(0.5f * p.w), v.w));
    out4[(size_t)i * 16 + lane] = z;                 // z
    out4[n16 + (size_t)i * 16 + lane] = v;           // mean
  } else {
    out4[2 * n16 + (size_t)i * 16 + (lane - 16)] = v;  // logvar
  }
}

}  // namespace

extern "C" void kernel_launch(void* const* d_in, const int* in_sizes, int n_in,
                              void* d_out, int out_size, void* d_ws, size_t ws_size,
                              hipStream_t stream) {
  const float* feature   = (const float*)d_in[0];
  const float* condition = (const float*)d_in[1];
  const int*   ei        = (const int*)d_in[2];
  const float* noise     = (const float*)d_in[3];
  const float* W_f2h     = (const float*)d_in[4];
  const float* b_f2h     = (const float*)d_in[5];
  const float* W_c2h     = (const float*)d_in[6];
  const float* b_c2h     = (const float*)d_in[7];
  const float* W_h2h     = (const float*)d_in[8];
  const float* b_h2h     = (const float*)d_in[9];
  const float* W_mean    = (const float*)d_in[10];
  const float* b_mean    = (const float*)d_in[11];
  const float* W_logvar  = (const float*)d_in[12];
  const float* b_logvar  = (const float*)d_in[13];

  const int* src = ei;
  const int* dst = ei + E;

  char* p = (char*)d_ws;
  auto alloc = [&](size_t bytes) {
    char* q = p;
    p += (bytes + 255) & ~(size_t)255;
    return q;
  };
  float* bufA    = (float*)alloc((size_t)N * 128 * 4);   // f2h, then v
  float* bufB    = (float*)alloc((size_t)N * 128 * 4);   // c2h
  float* bufC    = (float*)alloc((size_t)N * 128 * 4);   // Pc, then h
  unsigned short* bfX = (unsigned short*)alloc((size_t)N * 128 * 2);  // uf, then u2
  unsigned short* bfC = (unsigned short*)alloc((size_t)N * 64 * 2);   // condbf
  int*   cnt     = (int*)alloc((size_t)N * 4);
  int*   row_ptr = (int*)alloc((size_t)(N + 1) * 4);
  int*   cursor  = (int*)alloc((size_t)N * 4);
  int*   csr_src = (int*)alloc((size_t)E * 4);
  int*   bsum    = (int*)alloc(256 * 4);
  float* dinv    = (float*)alloc((size_t)N * 4);
  float* Wcat    = (float*)alloc(128 * 128 * 4);
  float* bcat    = (float*)alloc(128 * 4);
  (void)ws_size; (void)in_sizes; (void)n_in; (void)out_size;

  int nb = (N + 255) / 256;

  // CSR build + norm
  zero_int<<<(N + 255) / 256, 256, 0, stream>>>(cnt, N);
  count_deg<<<(E + 255) / 256, 256, 0, stream>>>(dst, cnt, E);
  block_sums<<<nb, 256, 0, stream>>>(cnt, bsum, N);
  scan_bsums<<<1, 64, 0, stream>>>(bsum, nb);
  scan_chunks<<<nb, 256, 0, stream>>>(cnt, bsum, row_ptr, cursor, N);
  compute_dinv<<<(N + 255) / 256, 256, 0, stream>>>(cnt, dinv, N);
  scatter_edges<<<(E + 255) / 256, 256, 0, stream>>>(src, dst, cursor, csr_src, E);
  make_wcat<<<(128 * 128 + 255) / 256, 256, 0, stream>>>(W_mean, W_logvar, b_mean, b_logvar, Wcat, bcat);
  cvt_bf<<<(N * 16 + 255) / 256, 256, 0, stream>>>((const float4*)condition, (ushort4*)bfC, N * 16);

  int ggrid = (N + 63) / 64;

  // layer 1a: uf = feature@W_f2h (bf16); f2h = tanh(P(uf)+b) fp32
  gemm_tile<128, false, 2><<<ggrid, 256, 0, stream>>>(feature, nullptr, W_f2h, nullptr, bfX, N);
  prop_bf<128, 1><<<(N + 15) / 16, 256, 0, stream>>>(bfX, bufA, row_ptr, csr_src, dinv, b_f2h, N);
  // layer 1b (reordered): Pc = P(condbf) fp32 [N x 64]; c2h = tanh(Pc@W_c2h + b) fp32
  prop_bf<64, 0><<<(N + 31) / 32, 256, 0, stream>>>(bfC, bufC, row_ptr, csr_src, dinv, nullptr, N);
  gemm_tile<64, false, 1><<<ggrid, 256, 0, stream>>>(bufC, nullptr, W_c2h, b_c2h, bufB, N);
  // layer 2: u2 = cat(f2h,c2h)@W_h2h (bf16); h = tanh(P(u2)+b) fp32
  gemm_tile<256, true, 2><<<ggrid, 256, 0, stream>>>(bufA, bufB, W_h2h, nullptr, bfX, N);
  prop_bf<128, 1><<<(N + 15) / 16, 256, 0, stream>>>(bfX, bufC, row_ptr, csr_src, dinv, b_h2h, N);
  // layer 3: v = h@Wcat fp32; out = P(v)+bcat fused with reparam epilogue
  gemm_tile<128, false, 0><<<ggrid, 256, 0, stream>>>(bufC, nullptr, Wcat, nullptr, bufA, N);
  prop_fin<<<(N + 7) / 8, 256, 0, stream>>>((const float4*)bufA, row_ptr, csr_src, dinv,
                                            (const float4*)bcat, (const float4*)noise,
                                            (float*)d_out, N);
}

// Round 5
// 360.123 us; speedup vs baseline: 2.5489x; 1.2784x over previous
//
#include <hip/hip_runtime.h>
#include <math.h>

namespace {

constexpr int N = 50000;
constexpr int E = 800000;

typedef __attribute__((ext_vector_type(8))) short short8;   // 8 bf16 (4 VGPRs)
typedef __attribute__((ext_vector_type(4))) float f32x4;    // MFMA accum

// ---------- bf16 helpers (RTNE) ----------

__device__ inline unsigned short f2bf(float f) {
  unsigned int b = __float_as_uint(f);
  unsigned int r = (b + 0x7fffu + ((b >> 16) & 1u)) >> 16;
  return (unsigned short)r;
}
__device__ inline float bf_lo(unsigned int u) { return __uint_as_float(u << 16); }
__device__ inline float bf_hi(unsigned int u) { return __uint_as_float(u & 0xffff0000u); }
__device__ inline unsigned int pack2(float a, float b) {
  return (unsigned int)f2bf(a) | ((unsigned int)f2bf(b) << 16);
}

// ---------- CSR build ----------

__global__ void zero_int(int* p, int n) {
  int i = blockIdx.x * blockDim.x + threadIdx.x;
  if (i < n) p[i] = 0;
}

__global__ void count_deg(const int* __restrict__ dst, int* __restrict__ cnt, int e) {
  int i = blockIdx.x * blockDim.x + threadIdx.x;
  if (i < e) atomicAdd(&cnt[dst[i]], 1);
}

__global__ void block_sums(const int* __restrict__ cnt, int* __restrict__ bsum, int n) {
  int tid = threadIdx.x;
  int i = blockIdx.x * 256 + tid;
  int v = (i < n) ? cnt[i] : 0;
  for (int off = 32; off > 0; off >>= 1) v += __shfl_down(v, off, 64);
  __shared__ int sred[4];
  if ((tid & 63) == 0) sred[tid >> 6] = v;
  __syncthreads();
  if (tid == 0) bsum[blockIdx.x] = sred[0] + sred[1] + sred[2] + sred[3];
}

__global__ void scan_bsums(int* bsum, int nb) {
  if (threadIdx.x == 0 && blockIdx.x == 0) {
    int run = 0;
    for (int b = 0; b < nb; ++b) { int t = bsum[b]; bsum[b] = run; run += t; }
  }
}

__global__ void scan_chunks(const int* __restrict__ cnt, const int* __restrict__ bsum,
                            int* __restrict__ row_ptr, int* __restrict__ cursor, int n) {
  __shared__ int s[256];
  int tid = threadIdx.x;
  int i = blockIdx.x * 256 + tid;
  int v = (i < n) ? cnt[i] : 0;
  s[tid] = v;
  __syncthreads();
  for (int d = 1; d < 256; d <<= 1) {
    int t = (tid >= d) ? s[tid - d] : 0;
    __syncthreads();
    s[tid] += t;
    __syncthreads();
  }
  if (i < n) {
    int excl = bsum[blockIdx.x] + s[tid] - v;
    row_ptr[i] = excl;
    cursor[i] = excl;
    if (i == n - 1) row_ptr[n] = excl + v;
  }
}

__global__ void compute_dinv(const int* __restrict__ cnt, float* __restrict__ dinv, int n) {
  int i = blockIdx.x * blockDim.x + threadIdx.x;
  if (i < n) dinv[i] = rsqrtf((float)(cnt[i] + 1));
}

__global__ void scatter_edges(const int* __restrict__ src, const int* __restrict__ dst,
                              int* __restrict__ cursor, int* __restrict__ csr_src, int e) {
  int i = blockIdx.x * blockDim.x + threadIdx.x;
  if (i < e) {
    int d = dst[i];
    int pos = atomicAdd(&cursor[d], 1);
    csr_src[pos] = src[i];
  }
}

// ---------- conversions / weight packing ----------

__global__ void cvt_bf(const float4* __restrict__ in, ushort4* __restrict__ out, int n4) {
  int t = blockIdx.x * blockDim.x + threadIdx.x;
  if (t >= n4) return;
  float4 v = in[t];
  ushort4 o;
  o.x = f2bf(v.x); o.y = f2bf(v.y); o.z = f2bf(v.z); o.w = f2bf(v.w);
  out[t] = o;
}

// Pack W[K x 128] (optionally two col-split sources) into MFMA B-fragment order:
// out[((ks*8 + ct)*64 + lane)*8 + i] = W[ks*32 + (lane>>4)*8 + i][ct*16 + (lane&15)]
__global__ void pack_w(const float* __restrict__ W1, int s1,
                       const float* __restrict__ W2, int s2, int split,
                       int ksteps, unsigned short* __restrict__ out) {
  int t = blockIdx.x * blockDim.x + threadIdx.x;
  int total = ksteps * 8 * 64;
  if (t >= total) return;
  int ks = t >> 9;
  int ct = (t >> 6) & 7;
  int l = t & 63;
  int k0 = ks * 32 + ((l >> 4) << 3);
  int col = ct * 16 + (l & 15);
  const float* src;
  int c;
  if (col < split) { src = W1 + col; c = s1; }
  else { src = W2 + (col - split); c = s2; }
  unsigned short* o = out + (size_t)t * 8;
#pragma unroll
  for (int i = 0; i < 8; ++i) o[i] = f2bf(src[(size_t)(k0 + i) * c]);
}

__global__ void make_bcat(const float* __restrict__ bm, const float* __restrict__ bl,
                          float* __restrict__ bcat) {
  int j = threadIdx.x;
  if (j < 64) bcat[j] = bm[j];
  else if (j < 128) bcat[j] = bl[j - 64];
}

// ---------- MFMA GEMM: C[n x 128](bf16) = A[n x K](bf16, stride lda) @ Wp ----------
// 128 rows x 128 cols per 256-thread (4-wave) block. Each wave: 32 rows.
// EPI 0: plain bf16 store; EPI 1: tanh(acc + bias) bf16 store.

template <int K, int EPI>
__global__ __launch_bounds__(256) void gemm_mfma(const unsigned short* __restrict__ A, int lda,
                                                 const unsigned short* __restrict__ Wp,
                                                 const float* __restrict__ bias,
                                                 unsigned short* __restrict__ C, int ldc, int n) {
  constexpr int KSTEPS = K / 32;
  int tid = threadIdx.x;
  int w = tid >> 6;
  int l = tid & 63;
  int r0 = blockIdx.x * 128 + w * 32;
  int arow = l & 15;
  int kgrp = l >> 4;

  f32x4 acc[2][8];
#pragma unroll
  for (int m = 0; m < 2; ++m)
#pragma unroll
    for (int ct = 0; ct < 8; ++ct) acc[m][ct] = (f32x4)(0.f);

  int ra0 = min(r0 + arow, n - 1);
  int ra1 = min(r0 + 16 + arow, n - 1);
  const unsigned short* pa0 = A + (size_t)ra0 * lda + kgrp * 8;
  const unsigned short* pa1 = A + (size_t)ra1 * lda + kgrp * 8;

#pragma unroll 1
  for (int ks = 0; ks < KSTEPS; ++ks) {
    short8 a0 = *(const short8*)(pa0 + ks * 32);
    short8 a1 = *(const short8*)(pa1 + ks * 32);
    const short8* pb = (const short8*)Wp + (size_t)(ks * 8) * 64 + l;
#pragma unroll
    for (int ct = 0; ct < 8; ++ct) {
      short8 b = pb[ct * 64];
      acc[0][ct] = __builtin_amdgcn_mfma_f32_16x16x32_bf16(a0, b, acc[0][ct], 0, 0, 0);
      acc[1][ct] = __builtin_amdgcn_mfma_f32_16x16x32_bf16(a1, b, acc[1][ct], 0, 0, 0);
    }
  }

  int ccol = l & 15;
  int crow = (l >> 4) * 4;
#pragma unroll
  for (int ct = 0; ct < 8; ++ct) {
    int col = ct * 16 + ccol;
    float bv = (EPI == 1) ? bias[col] : 0.f;
#pragma unroll
    for (int m = 0; m < 2; ++m) {
#pragma unroll
      for (int r = 0; r < 4; ++r) {
        int row = r0 + m * 16 + crow + r;
        if (row < n) {
          float v = acc[m][ct][r];
          if (EPI == 1) v = tanhf(v + bv);
          C[(size_t)row * ldc + col] = f2bf(v);
        }
      }
    }
  }
}

// ---------- bf16 propagation: Y = act(dinv_i*(sum dinv_s*X[s] + dinv_i*X[i]) + b), bf16 out ----------

template <int COLS, int ACT>
__global__ __launch_bounds__(256) void prop_bf(const unsigned short* __restrict__ X,
                                               unsigned short* __restrict__ Y, int ldy,
                                               const int* __restrict__ row_ptr,
                                               const int* __restrict__ csr_src,
                                               const float* __restrict__ dinv,
                                               const float* __restrict__ bias, int n) {
  constexpr int LANES = COLS / 8;
  constexpr int RPB = 256 / LANES;
  int lane = threadIdx.x % LANES;
  int rloc = threadIdx.x / LANES;
  int i = blockIdx.x * RPB + rloc;
  if (i >= n) return;
  const uint4* X4 = (const uint4*)X;
  float di = dinv[i];
  float acc[8];
  {
    uint4 u = X4[(size_t)i * LANES + lane];
    acc[0] = di * bf_lo(u.x); acc[1] = di * bf_hi(u.x);
    acc[2] = di * bf_lo(u.y); acc[3] = di * bf_hi(u.y);
    acc[4] = di * bf_lo(u.z); acc[5] = di * bf_hi(u.z);
    acc[6] = di * bf_lo(u.w); acc[7] = di * bf_hi(u.w);
  }
  int e0 = row_ptr[i], e1 = row_ptr[i + 1];
  for (int e = e0; e < e1; ++e) {
    int s = csr_src[e];
    float dv = dinv[s];
    uint4 u = X4[(size_t)s * LANES + lane];
    acc[0] = fmaf(dv, bf_lo(u.x), acc[0]); acc[1] = fmaf(dv, bf_hi(u.x), acc[1]);
    acc[2] = fmaf(dv, bf_lo(u.y), acc[2]); acc[3] = fmaf(dv, bf_hi(u.y), acc[3]);
    acc[4] = fmaf(dv, bf_lo(u.z), acc[4]); acc[5] = fmaf(dv, bf_hi(u.z), acc[5]);
    acc[6] = fmaf(dv, bf_lo(u.w), acc[6]); acc[7] = fmaf(dv, bf_hi(u.w), acc[7]);
  }
  float out[8];
  if (ACT) {
#pragma unroll
    for (int j = 0; j < 8; ++j) out[j] = tanhf(fmaf(di, acc[j], bias[lane * 8 + j]));
  } else {
#pragma unroll
    for (int j = 0; j < 8; ++j) out[j] = di * acc[j];
  }
  uint4 o;
  o.x = pack2(out[0], out[1]);
  o.y = pack2(out[2], out[3]);
  o.z = pack2(out[4], out[5]);
  o.w = pack2(out[6], out[7]);
  *(uint4*)(Y + (size_t)i * ldy + lane * 8) = o;
}

// ---------- final prop (bf16 gather) + fused reparam epilogue ----------
// lanes 0-7: mean cols (0-63); lanes 8-15: logvar cols (64-127).

__global__ __launch_bounds__(256) void prop_fin_bf(const unsigned short* __restrict__ X,
                                                   const int* __restrict__ row_ptr,
                                                   const int* __restrict__ csr_src,
                                                   const float* __restrict__ dinv,
                                                   const float* __restrict__ bcat,
                                                   const float* __restrict__ noise,
                                                   float* __restrict__ out, int n) {
  int lane = threadIdx.x & 15;
  int rloc = threadIdx.x >> 4;
  int i = blockIdx.x * 16 + rloc;
  if (i >= n) return;
  const uint4* X4 = (const uint4*)X;
  float di = dinv[i];
  float acc[8];
  {
    uint4 u = X4[(size_t)i * 16 + lane];
    acc[0] = di * bf_lo(u.x); acc[1] = di * bf_hi(u.x);
    acc[2] = di * bf_lo(u.y); acc[3] = di * bf_hi(u.y);
    acc[4] = di * bf_lo(u.z); acc[5] = di * bf_hi(u.z);
    acc[6] = di * bf_lo(u.w); acc[7] = di * bf_hi(u.w);
  }
  int e0 = row_ptr[i], e1 = row_ptr[i + 1];
  for (int e = e0; e < e1; ++e) {
    int s = csr_src[e];
    float dv = dinv[s];
    uint4 u = X4[(size_t)s * 16 + lane];
    acc[0] = fmaf(dv, bf_lo(u.x), acc[0]); acc[1] = fmaf(dv, bf_hi(u.x), acc[1]);
    acc[2] = fmaf(dv, bf_lo(u.y), acc[2]); acc[3] = fmaf(dv, bf_hi(u.y), acc[3]);
    acc[4] = fmaf(dv, bf_lo(u.z), acc[4]); acc[5] = fmaf(dv, bf_hi(u.z), acc[5]);
    acc[6] = fmaf(dv, bf_lo(u.w), acc[6]); acc[7] = fmaf(dv, bf_hi(u.w), acc[7]);
  }
  float v[8];
#pragma unroll
  for (int j = 0; j < 8; ++j) v[j] = fmaf(di, acc[j], bcat[lane * 8 + j]);
  float p[8];
#pragma unroll
  for (int j = 0; j < 8; ++j) p[j] = __shfl_xor(v[j], 8);
  size_t n64 = (size_t)n * 64;
  if (lane < 8) {
    // v = mean, p = logvar
    const float* nz = noise + (size_t)i * 64 + lane * 8;
    float z[8];
#pragma unroll
    for (int j = 0; j < 8; ++j) z[j] = fmaf(nz[j], expf(0.5f * p[j]), v[j]);
    float* zp = out + (size_t)i * 64 + lane * 8;
    *(float4*)zp = make_float4(z[0], z[1], z[2], z[3]);
    *(float4*)(zp + 4) = make_float4(z[4], z[5], z[6], z[7]);
    float* mp = out + n64 + (size_t)i * 64 + lane * 8;
    *(float4*)mp = make_float4(v[0], v[1], v[2], v[3]);
    *(float4*)(mp + 4) = make_float4(v[4], v[5], v[6], v[7]);
  } else {
    float* lp = out + 2 * n64 + (size_t)i * 64 + (lane - 8) * 8;
    *(float4*)lp = make_float4(v[0], v[1], v[2], v[3]);
    *(float4*)(lp + 4) = make_float4(v[4], v[5], v[6], v[7]);
  }
}

}  // namespace

extern "C" void kernel_launch(void* const* d_in, const int* in_sizes, int n_in,
                              void* d_out, int out_size, void* d_ws, size_t ws_size,
                              hipStream_t stream) {
  const float* feature   = (const float*)d_in[0];
  const float* condition = (const float*)d_in[1];
  const int*   ei        = (const int*)d_in[2];
  const float* noise     = (const float*)d_in[3];
  const float* W_f2h     = (const float*)d_in[4];
  const float* b_f2h     = (const float*)d_in[5];
  const float* W_c2h     = (const float*)d_in[6];
  const float* b_c2h     = (const float*)d_in[7];
  const float* W_h2h     = (const float*)d_in[8];
  const float* b_h2h     = (const float*)d_in[9];
  const float* W_mean    = (const float*)d_in[10];
  const float* b_mean    = (const float*)d_in[11];
  const float* W_logvar  = (const float*)d_in[12];
  const float* b_logvar  = (const float*)d_in[13];

  const int* src = ei;
  const int* dst = ei + E;

  char* p = (char*)d_ws;
  auto alloc = [&](size_t bytes) {
    char* q = p;
    p += (bytes + 255) & ~(size_t)255;
    return q;
  };
  unsigned short* bufF   = (unsigned short*)alloc((size_t)N * 128 * 2);  // featbf, then h
  unsigned short* bufU   = (unsigned short*)alloc((size_t)N * 128 * 2);  // uf, u2, v
  unsigned short* catbuf = (unsigned short*)alloc((size_t)N * 256 * 2);  // [f2h | c2h]
  unsigned short* condbf = (unsigned short*)alloc((size_t)N * 64 * 2);
  unsigned short* Pcbf   = (unsigned short*)alloc((size_t)N * 64 * 2);
  int*   cnt     = (int*)alloc((size_t)N * 4);
  int*   row_ptr = (int*)alloc((size_t)(N + 1) * 4);
  int*   cursor  = (int*)alloc((size_t)N * 4);
  int*   csr_src = (int*)alloc((size_t)E * 4);
  int*   bsum    = (int*)alloc(256 * 4);
  float* dinv    = (float*)alloc((size_t)N * 4);
  unsigned short* Wf2h_p = (unsigned short*)alloc(4 * 512 * 8 * 2);
  unsigned short* Wc2h_p = (unsigned short*)alloc(2 * 512 * 8 * 2);
  unsigned short* Wh2h_p = (unsigned short*)alloc(8 * 512 * 8 * 2);
  unsigned short* Wcat_p = (unsigned short*)alloc(4 * 512 * 8 * 2);
  float* bcat    = (float*)alloc(128 * 4);
  (void)ws_size; (void)in_sizes; (void)n_in; (void)out_size;

  int nb = (N + 255) / 256;

  // CSR build + norm
  zero_int<<<(N + 255) / 256, 256, 0, stream>>>(cnt, N);
  count_deg<<<(E + 255) / 256, 256, 0, stream>>>(dst, cnt, E);
  block_sums<<<nb, 256, 0, stream>>>(cnt, bsum, N);
  scan_bsums<<<1, 64, 0, stream>>>(bsum, nb);
  scan_chunks<<<nb, 256, 0, stream>>>(cnt, bsum, row_ptr, cursor, N);
  compute_dinv<<<(N + 255) / 256, 256, 0, stream>>>(cnt, dinv, N);
  scatter_edges<<<(E + 255) / 256, 256, 0, stream>>>(src, dst, cursor, csr_src, E);

  // conversions + weight packing
  cvt_bf<<<(N * 32 + 255) / 256, 256, 0, stream>>>((const float4*)feature, (ushort4*)bufF, N * 32);
  cvt_bf<<<(N * 16 + 255) / 256, 256, 0, stream>>>((const float4*)condition, (ushort4*)condbf, N * 16);
  pack_w<<<(4 * 512 + 255) / 256, 256, 0, stream>>>(W_f2h, 128, nullptr, 0, 128, 4, Wf2h_p);
  pack_w<<<(2 * 512 + 255) / 256, 256, 0, stream>>>(W_c2h, 128, nullptr, 0, 128, 2, Wc2h_p);
  pack_w<<<(8 * 512 + 255) / 256, 256, 0, stream>>>(W_h2h, 128, nullptr, 0, 128, 8, Wh2h_p);
  pack_w<<<(4 * 512 + 255) / 256, 256, 0, stream>>>(W_mean, 64, W_logvar, 64, 64, 4, Wcat_p);
  make_bcat<<<1, 128, 0, stream>>>(b_mean, b_logvar, bcat);

  int ggrid = (N + 127) / 128;  // 391

  // L1a: uf = featbf @ W_f2h ; f2h = tanh(P(uf)+b) -> catbuf[:,0:128]
  gemm_mfma<128, 0><<<ggrid, 256, 0, stream>>>(bufF, 128, Wf2h_p, nullptr, bufU, 128, N);
  prop_bf<128, 1><<<(N + 15) / 16, 256, 0, stream>>>(bufU, catbuf, 256, row_ptr, csr_src, dinv, b_f2h, N);
  // L1b: Pc = P(condbf) ; c2h = tanh(Pc @ W_c2h + b) -> catbuf[:,128:256]
  prop_bf<64, 0><<<(N + 31) / 32, 256, 0, stream>>>(condbf, Pcbf, 64, row_ptr, csr_src, dinv, nullptr, N);
  gemm_mfma<64, 1><<<ggrid, 256, 0, stream>>>(Pcbf, 64, Wc2h_p, b_c2h, catbuf + 128, 256, N);
  // L2: u2 = catbuf @ W_h2h ; h = tanh(P(u2)+b) -> bufF
  gemm_mfma<256, 0><<<ggrid, 256, 0, stream>>>(catbuf, 256, Wh2h_p, nullptr, bufU, 128, N);
  prop_bf<128, 1><<<(N + 15) / 16, 256, 0, stream>>>(bufU, bufF, 128, row_ptr, csr_src, dinv, b_h2h, N);
  // L3: v = h @ [W_mean|W_logvar] ; out = P(v)+bcat fused with reparam
  gemm_mfma<128, 0><<<ggrid, 256, 0, stream>>>(bufF, 128, Wcat_p, nullptr, bufU, 128, N);
  prop_fin_bf<<<(N + 15) / 16, 256, 0, stream>>>(bufU, row_ptr, csr_src, dinv, bcat, noise,
                                                 (float*)d_out, N);
}

// Round 6
// 298.655 us; speedup vs baseline: 3.0735x; 1.2058x over previous
//
#include <hip/hip_runtime.h>
#include <math.h>

namespace {

constexpr int N = 50000;
constexpr int E = 800000;

typedef __attribute__((ext_vector_type(8))) short short8;   // 8 bf16 (4 VGPRs)
typedef __attribute__((ext_vector_type(4))) float f32x4;    // MFMA accum

// ---------- bf16 helpers (RTNE) ----------

__device__ inline unsigned short f2bf(float f) {
  unsigned int b = __float_as_uint(f);
  unsigned int r = (b + 0x7fffu + ((b >> 16) & 1u)) >> 16;
  return (unsigned short)r;
}
__device__ inline float bf_lo(unsigned int u) { return __uint_as_float(u << 16); }
__device__ inline float bf_hi(unsigned int u) { return __uint_as_float(u & 0xffff0000u); }
__device__ inline unsigned int pack2(float a, float b) {
  return (unsigned int)f2bf(a) | ((unsigned int)f2bf(b) << 16);
}

// ---------- CSR build ----------

__global__ void zero_int(int* p, int n) {
  int i = blockIdx.x * blockDim.x + threadIdx.x;
  if (i < n) p[i] = 0;
}

// count in-degree AND capture each edge's rank within its dst (coalesced write)
__global__ void count_deg_rank(const int* __restrict__ dst, int* __restrict__ cnt,
                               int* __restrict__ rank, int e) {
  int i = blockIdx.x * blockDim.x + threadIdx.x;
  if (i < e) rank[i] = atomicAdd(&cnt[dst[i]], 1);
}

__global__ void block_sums(const int* __restrict__ cnt, int* __restrict__ bsum, int n) {
  int tid = threadIdx.x;
  int i = blockIdx.x * 256 + tid;
  int v = (i < n) ? cnt[i] : 0;
  for (int off = 32; off > 0; off >>= 1) v += __shfl_down(v, off, 64);
  __shared__ int sred[4];
  if ((tid & 63) == 0) sred[tid >> 6] = v;
  __syncthreads();
  if (tid == 0) bsum[blockIdx.x] = sred[0] + sred[1] + sred[2] + sred[3];
}

__global__ void scan_bsums(int* bsum, int nb) {
  if (threadIdx.x == 0 && blockIdx.x == 0) {
    int run = 0;
    for (int b = 0; b < nb; ++b) { int t = bsum[b]; bsum[b] = run; run += t; }
  }
}

__global__ void scan_chunks(const int* __restrict__ cnt, const int* __restrict__ bsum,
                            int* __restrict__ row_ptr, int n) {
  __shared__ int s[256];
  int tid = threadIdx.x;
  int i = blockIdx.x * 256 + tid;
  int v = (i < n) ? cnt[i] : 0;
  s[tid] = v;
  __syncthreads();
  for (int d = 1; d < 256; d <<= 1) {
    int t = (tid >= d) ? s[tid - d] : 0;
    __syncthreads();
    s[tid] += t;
    __syncthreads();
  }
  if (i < n) {
    int excl = bsum[blockIdx.x] + s[tid] - v;
    row_ptr[i] = excl;
    if (i == n - 1) row_ptr[n] = excl + v;
  }
}

__global__ void compute_dinv(const int* __restrict__ cnt, float* __restrict__ dinv, int n) {
  int i = blockIdx.x * blockDim.x + threadIdx.x;
  if (i < n) dinv[i] = rsqrtf((float)(cnt[i] + 1));
}

// XCD-filtered scatter: range-group r = blockIdx&7 handles dst in [r*6250,(r+1)*6250).
// With round-robin block->XCD dispatch each csr region is written by one XCD only,
// so scattered 4B writes accumulate in that XCD's L2 instead of thrashing HBM.
// No atomics: pos = row_ptr[d] + rank[e]. Correct regardless of XCD mapping.
__global__ __launch_bounds__(256) void scatter_xcd(const int* __restrict__ src,
                                                   const int* __restrict__ dst,
                                                   const int* __restrict__ rank,
                                                   const int* __restrict__ row_ptr,
                                                   int* __restrict__ csr_src) {
  constexpr int RANGE = (N + 7) / 8;  // 6250
  int r = blockIdx.x & 7;
  int lo = r * RANGE;
  int hi = lo + RANGE;  // 8*6250 == N exactly
  int nb = gridDim.x >> 3;
  int bi = blockIdx.x >> 3;
  for (int e = bi * 256 + threadIdx.x; e < E; e += nb * 256) {
    int d = dst[e];
    if (d >= lo && d < hi) {
      csr_src[row_ptr[d] + rank[e]] = src[e];
    }
  }
}

// ---------- conversions / weight packing ----------

// convert condition fp32 [N x 64] into buf192 cols 128..191 (bf16, stride 192)
__global__ void cvt_cond(const float* __restrict__ in, unsigned short* __restrict__ out, int n) {
  int t = blockIdx.x * blockDim.x + threadIdx.x;
  if (t >= n * 8) return;
  int i = t >> 3, j = t & 7;
  const float* s = in + (size_t)i * 64 + j * 8;
  float4 a = *(const float4*)s;
  float4 b = *(const float4*)(s + 4);
  uint4 o;
  o.x = pack2(a.x, a.y);
  o.y = pack2(a.z, a.w);
  o.z = pack2(b.x, b.y);
  o.w = pack2(b.z, b.w);
  *(uint4*)(out + (size_t)i * 192 + 128 + j * 8) = o;
}

// Pack W[K x 128] (optionally two col-split sources) into MFMA B-fragment order:
// out[((ks*8 + ct)*64 + lane)*8 + i] = W[ks*32 + (lane>>4)*8 + i][ct*16 + (lane&15)]
__global__ void pack_w(const float* __restrict__ W1, int s1,
                       const float* __restrict__ W2, int s2, int split,
                       int ksteps, unsigned short* __restrict__ out) {
  int t = blockIdx.x * blockDim.x + threadIdx.x;
  int total = ksteps * 8 * 64;
  if (t >= total) return;
  int ks = t >> 9;
  int ct = (t >> 6) & 7;
  int l = t & 63;
  int k0 = ks * 32 + ((l >> 4) << 3);
  int col = ct * 16 + (l & 15);
  const float* src;
  int c;
  if (col < split) { src = W1 + col; c = s1; }
  else { src = W2 + (col - split); c = s2; }
  unsigned short* o = out + (size_t)t * 8;
#pragma unroll
  for (int i = 0; i < 8; ++i) o[i] = f2bf(src[(size_t)(k0 + i) * c]);
}

__global__ void make_bcat(const float* __restrict__ bm, const float* __restrict__ bl,
                          float* __restrict__ bcat) {
  int j = threadIdx.x;
  if (j < 64) bcat[j] = bm[j];
  else if (j < 128) bcat[j] = bl[j - 64];
}

// ---------- MFMA GEMM: C[n x 128](bf16) = A[n x K] @ Wp ----------
// 128 rows x 128 cols per 256-thread (4-wave) block. F32A: A is fp32 (converted in-reg).
// EPI 0: plain bf16 store; EPI 1: tanh(acc + bias) bf16 store.

template <int K, int EPI, bool F32A>
__global__ __launch_bounds__(256) void gemm_mfma(const void* __restrict__ Av, int lda,
                                                 const unsigned short* __restrict__ Wp,
                                                 const float* __restrict__ bias,
                                                 unsigned short* __restrict__ C, int ldc, int n) {
  constexpr int KSTEPS = K / 32;
  int tid = threadIdx.x;
  int w = tid >> 6;
  int l = tid & 63;
  int r0 = blockIdx.x * 128 + w * 32;
  int arow = l & 15;
  int kgrp = l >> 4;

  f32x4 acc[2][8];
#pragma unroll
  for (int m = 0; m < 2; ++m)
#pragma unroll
    for (int ct = 0; ct < 8; ++ct) acc[m][ct] = (f32x4)(0.f);

  int ra0 = min(r0 + arow, n - 1);
  int ra1 = min(r0 + 16 + arow, n - 1);

#pragma unroll 1
  for (int ks = 0; ks < KSTEPS; ++ks) {
    short8 a0, a1;
    if (F32A) {
      const float* p0 = (const float*)Av + (size_t)ra0 * lda + kgrp * 8 + ks * 32;
      const float* p1 = (const float*)Av + (size_t)ra1 * lda + kgrp * 8 + ks * 32;
      float4 x0 = *(const float4*)p0, y0 = *(const float4*)(p0 + 4);
      float4 x1 = *(const float4*)p1, y1 = *(const float4*)(p1 + 4);
      unsigned int u[4];
      u[0] = pack2(x0.x, x0.y); u[1] = pack2(x0.z, x0.w);
      u[2] = pack2(y0.x, y0.y); u[3] = pack2(y0.z, y0.w);
      a0 = *(const short8*)u;
      u[0] = pack2(x1.x, x1.y); u[1] = pack2(x1.z, x1.w);
      u[2] = pack2(y1.x, y1.y); u[3] = pack2(y1.z, y1.w);
      a1 = *(const short8*)u;
    } else {
      a0 = *(const short8*)((const unsigned short*)Av + (size_t)ra0 * lda + kgrp * 8 + ks * 32);
      a1 = *(const short8*)((const unsigned short*)Av + (size_t)ra1 * lda + kgrp * 8 + ks * 32);
    }
    const short8* pb = (const short8*)Wp + (size_t)(ks * 8) * 64 + l;
#pragma unroll
    for (int ct = 0; ct < 8; ++ct) {
      short8 b = pb[ct * 64];
      acc[0][ct] = __builtin_amdgcn_mfma_f32_16x16x32_bf16(a0, b, acc[0][ct], 0, 0, 0);
      acc[1][ct] = __builtin_amdgcn_mfma_f32_16x16x32_bf16(a1, b, acc[1][ct], 0, 0, 0);
    }
  }

  int ccol = l & 15;
  int crow = (l >> 4) * 4;
#pragma unroll
  for (int ct = 0; ct < 8; ++ct) {
    int col = ct * 16 + ccol;
    float bv = (EPI == 1) ? bias[col] : 0.f;
#pragma unroll
    for (int m = 0; m < 2; ++m) {
#pragma unroll
      for (int r = 0; r < 4; ++r) {
        int row = r0 + m * 16 + crow + r;
        if (row < n) {
          float v = acc[m][ct][r];
          if (EPI == 1) v = tanhf(v + bv);
          C[(size_t)row * ldc + col] = f2bf(v);
        }
      }
    }
  }
}

// ---------- edge-gather accumulate helpers ----------

#define ACC8_INIT(ACC, U, D)                                        \
  ACC[0] = D * bf_lo(U.x); ACC[1] = D * bf_hi(U.x);                 \
  ACC[2] = D * bf_lo(U.y); ACC[3] = D * bf_hi(U.y);                 \
  ACC[4] = D * bf_lo(U.z); ACC[5] = D * bf_hi(U.z);                 \
  ACC[6] = D * bf_lo(U.w); ACC[7] = D * bf_hi(U.w);

#define ACC8_FMA(ACC, U, D)                                         \
  ACC[0] = fmaf(D, bf_lo(U.x), ACC[0]); ACC[1] = fmaf(D, bf_hi(U.x), ACC[1]); \
  ACC[2] = fmaf(D, bf_lo(U.y), ACC[2]); ACC[3] = fmaf(D, bf_hi(U.y), ACC[3]); \
  ACC[4] = fmaf(D, bf_lo(U.z), ACC[4]); ACC[5] = fmaf(D, bf_hi(U.z), ACC[5]); \
  ACC[6] = fmaf(D, bf_lo(U.w), ACC[6]); ACC[7] = fmaf(D, bf_hi(U.w), ACC[7]);

// 2-way unrolled edge walk: acc (even) + acc2 (odd), merged by caller.
#define EDGE_WALK(LANES)                                            \
  int e = e0;                                                       \
  for (; e + 2 <= e1; e += 2) {                                     \
    int s0 = csr_src[e], s1 = csr_src[e + 1];                       \
    float d0 = dinv[s0], d1 = dinv[s1];                             \
    uint4 u0 = X4[(size_t)s0 * LANES + lane];                       \
    uint4 u1 = X4[(size_t)s1 * LANES + lane];                       \
    ACC8_FMA(acc, u0, d0)                                           \
    ACC8_FMA(acc2, u1, d1)                                          \
  }                                                                 \
  if (e < e1) {                                                     \
    int s0 = csr_src[e];                                            \
    float d0 = dinv[s0];                                            \
    uint4 u0 = X4[(size_t)s0 * LANES + lane];                       \
    ACC8_FMA(acc, u0, d0)                                           \
  }                                                                 \
  _Pragma("unroll")                                                 \
  for (int j = 0; j < 8; ++j) acc[j] += acc2[j];

// ---------- fused first-layer prop over 192 cols: [uf(128) | cond(64)] ----------
// lanes 0-15 -> f2h = tanh(di*acc + b_f2h) into catbuf (stride 256)
// lanes 16-23 -> Pc = di*acc into Pcbf (stride 64)
// 192 threads/block (3 waves), 8 rows/block.

__global__ __launch_bounds__(192) void prop192(const unsigned short* __restrict__ X,
                                               unsigned short* __restrict__ f2h_out,
                                               unsigned short* __restrict__ pc_out,
                                               const int* __restrict__ row_ptr,
                                               const int* __restrict__ csr_src,
                                               const float* __restrict__ dinv,
                                               const float* __restrict__ b_f2h, int n) {
  constexpr int LANES = 24;
  int lane = threadIdx.x % LANES;
  int rloc = threadIdx.x / LANES;
  int i = blockIdx.x * 8 + rloc;
  if (i >= n) return;
  const uint4* X4 = (const uint4*)X;
  float di = dinv[i];
  float acc[8], acc2[8];
  {
    uint4 u = X4[(size_t)i * LANES + lane];
    ACC8_INIT(acc, u, di)
  }
#pragma unroll
  for (int j = 0; j < 8; ++j) acc2[j] = 0.f;
  int e0 = row_ptr[i], e1 = row_ptr[i + 1];
  EDGE_WALK(24)
  if (lane < 16) {
    float out[8];
#pragma unroll
    for (int j = 0; j < 8; ++j) out[j] = tanhf(fmaf(di, acc[j], b_f2h[lane * 8 + j]));
    uint4 o;
    o.x = pack2(out[0], out[1]); o.y = pack2(out[2], out[3]);
    o.z = pack2(out[4], out[5]); o.w = pack2(out[6], out[7]);
    *(uint4*)(f2h_out + (size_t)i * 256 + lane * 8) = o;
  } else {
    uint4 o;
    o.x = pack2(di * acc[0], di * acc[1]); o.y = pack2(di * acc[2], di * acc[3]);
    o.z = pack2(di * acc[4], di * acc[5]); o.w = pack2(di * acc[6], di * acc[7]);
    *(uint4*)(pc_out + (size_t)i * 64 + (lane - 16) * 8) = o;
  }
}

// ---------- 128-col bf16 prop with tanh+bias ----------

__global__ __launch_bounds__(256) void prop128(const unsigned short* __restrict__ X,
                                               unsigned short* __restrict__ Y,
                                               const int* __restrict__ row_ptr,
                                               const int* __restrict__ csr_src,
                                               const float* __restrict__ dinv,
                                               const float* __restrict__ bias, int n) {
  constexpr int LANES = 16;
  int lane = threadIdx.x % LANES;
  int rloc = threadIdx.x / LANES;
  int i = blockIdx.x * 16 + rloc;
  if (i >= n) return;
  const uint4* X4 = (const uint4*)X;
  float di = dinv[i];
  float acc[8], acc2[8];
  {
    uint4 u = X4[(size_t)i * LANES + lane];
    ACC8_INIT(acc, u, di)
  }
#pragma unroll
  for (int j = 0; j < 8; ++j) acc2[j] = 0.f;
  int e0 = row_ptr[i], e1 = row_ptr[i + 1];
  EDGE_WALK(16)
  float out[8];
#pragma unroll
  for (int j = 0; j < 8; ++j) out[j] = tanhf(fmaf(di, acc[j], bias[lane * 8 + j]));
  uint4 o;
  o.x = pack2(out[0], out[1]); o.y = pack2(out[2], out[3]);
  o.z = pack2(out[4], out[5]); o.w = pack2(out[6], out[7]);
  *(uint4*)(Y + (size_t)i * 128 + lane * 8) = o;
}

// ---------- final prop (bf16 gather) + fused reparam epilogue ----------
// lanes 0-7: mean cols (0-63); lanes 8-15: logvar cols (64-127).

__global__ __launch_bounds__(256) void prop_fin_bf(const unsigned short* __restrict__ X,
                                                   const int* __restrict__ row_ptr,
                                                   const int* __restrict__ csr_src,
                                                   const float* __restrict__ dinv,
                                                   const float* __restrict__ bcat,
                                                   const float* __restrict__ noise,
                                                   float* __restrict__ out, int n) {
  constexpr int LANES = 16;
  int lane = threadIdx.x & 15;
  int rloc = threadIdx.x >> 4;
  int i = blockIdx.x * 16 + rloc;
  if (i >= n) return;
  const uint4* X4 = (const uint4*)X;
  float di = dinv[i];
  float acc[8], acc2[8];
  {
    uint4 u = X4[(size_t)i * LANES + lane];
    ACC8_INIT(acc, u, di)
  }
#pragma unroll
  for (int j = 0; j < 8; ++j) acc2[j] = 0.f;
  int e0 = row_ptr[i], e1 = row_ptr[i + 1];
  EDGE_WALK(16)
  float v[8];
#pragma unroll
  for (int j = 0; j < 8; ++j) v[j] = fmaf(di, acc[j], bcat[lane * 8 + j]);
  float p[8];
#pragma unroll
  for (int j = 0; j < 8; ++j) p[j] = __shfl_xor(v[j], 8);
  size_t n64 = (size_t)n * 64;
  if (lane < 8) {
    // v = mean, p = logvar
    const float* nz = noise + (size_t)i * 64 + lane * 8;
    float z[8];
#pragma unroll
    for (int j = 0; j < 8; ++j) z[j] = fmaf(nz[j], expf(0.5f * p[j]), v[j]);
    float* zp = out + (size_t)i * 64 + lane * 8;
    *(float4*)zp = make_float4(z[0], z[1], z[2], z[3]);
    *(float4*)(zp + 4) = make_float4(z[4], z[5], z[6], z[7]);
    float* mp = out + n64 + (size_t)i * 64 + lane * 8;
    *(float4*)mp = make_float4(v[0], v[1], v[2], v[3]);
    *(float4*)(mp + 4) = make_float4(v[4], v[5], v[6], v[7]);
  } else {
    float* lp = out + 2 * n64 + (size_t)i * 64 + (lane - 8) * 8;
    *(float4*)lp = make_float4(v[0], v[1], v[2], v[3]);
    *(float4*)(lp + 4) = make_float4(v[4], v[5], v[6], v[7]);
  }
}

}  // namespace

extern "C" void kernel_launch(void* const* d_in, const int* in_sizes, int n_in,
                              void* d_out, int out_size, void* d_ws, size_t ws_size,
                              hipStream_t stream) {
  const float* feature   = (const float*)d_in[0];
  const float* condition = (const float*)d_in[1];
  const int*   ei        = (const int*)d_in[2];
  const float* noise     = (const float*)d_in[3];
  const float* W_f2h     = (const float*)d_in[4];
  const float* b_f2h     = (const float*)d_in[5];
  const float* W_c2h     = (const float*)d_in[6];
  const float* b_c2h     = (const float*)d_in[7];
  const float* W_h2h     = (const float*)d_in[8];
  const float* b_h2h     = (const float*)d_in[9];
  const float* W_mean    = (const float*)d_in[10];
  const float* b_mean    = (const float*)d_in[11];
  const float* W_logvar  = (const float*)d_in[12];
  const float* b_logvar  = (const float*)d_in[13];

  const int* src = ei;
  const int* dst = ei + E;

  char* p = (char*)d_ws;
  auto alloc = [&](size_t bytes) {
    char* q = p;
    p += (bytes + 255) & ~(size_t)255;
    return q;
  };
  unsigned short* buf192 = (unsigned short*)alloc((size_t)N * 192 * 2);  // [uf|cond], later h
  unsigned short* bufU   = (unsigned short*)alloc((size_t)N * 128 * 2);  // u2, v
  unsigned short* catbuf = (unsigned short*)alloc((size_t)N * 256 * 2);  // [f2h | c2h]
  unsigned short* Pcbf   = (unsigned short*)alloc((size_t)N * 64 * 2);
  int*   cnt     = (int*)alloc((size_t)N * 4);
  int*   rank    = (int*)alloc((size_t)E * 4);
  int*   row_ptr = (int*)alloc((size_t)(N + 1) * 4);
  int*   csr_src = (int*)alloc((size_t)E * 4);
  int*   bsum    = (int*)alloc(256 * 4);
  float* dinv    = (float*)alloc((size_t)N * 4);
  unsigned short* Wf2h_p = (unsigned short*)alloc(4 * 512 * 8 * 2);
  unsigned short* Wc2h_p = (unsigned short*)alloc(2 * 512 * 8 * 2);
  unsigned short* Wh2h_p = (unsigned short*)alloc(8 * 512 * 8 * 2);
  unsigned short* Wcat_p = (unsigned short*)alloc(4 * 512 * 8 * 2);
  float* bcat    = (float*)alloc(128 * 4);
  unsigned short* hbuf = buf192;  // alias: buf192 dead after prop192
  (void)ws_size; (void)in_sizes; (void)n_in; (void)out_size;

  int nb = (N + 255) / 256;

  // CSR build + norm (rank captured during counting; scatter is atomic-free)
  zero_int<<<(N + 255) / 256, 256, 0, stream>>>(cnt, N);
  count_deg_rank<<<(E + 255) / 256, 256, 0, stream>>>(dst, cnt, rank, E);
  block_sums<<<nb, 256, 0, stream>>>(cnt, bsum, N);
  scan_bsums<<<1, 64, 0, stream>>>(bsum, nb);
  scan_chunks<<<nb, 256, 0, stream>>>(cnt, bsum, row_ptr, N);
  compute_dinv<<<(N + 255) / 256, 256, 0, stream>>>(cnt, dinv, N);
  scatter_xcd<<<1024, 256, 0, stream>>>(src, dst, rank, row_ptr, csr_src);

  // conversions + weight packing
  cvt_cond<<<(N * 8 + 255) / 256, 256, 0, stream>>>(condition, buf192, N);
  pack_w<<<(4 * 512 + 255) / 256, 256, 0, stream>>>(W_f2h, 128, nullptr, 0, 128, 4, Wf2h_p);
  pack_w<<<(2 * 512 + 255) / 256, 256, 0, stream>>>(W_c2h, 128, nullptr, 0, 128, 2, Wc2h_p);
  pack_w<<<(8 * 512 + 255) / 256, 256, 0, stream>>>(W_h2h, 128, nullptr, 0, 128, 8, Wh2h_p);
  pack_w<<<(4 * 512 + 255) / 256, 256, 0, stream>>>(W_mean, 64, W_logvar, 64, 64, 4, Wcat_p);
  make_bcat<<<1, 128, 0, stream>>>(b_mean, b_logvar, bcat);

  int ggrid = (N + 127) / 128;  // 391

  // L1: uf = feature @ W_f2h (fp32 A, bf16 out, into buf192 cols 0-127)
  gemm_mfma<128, 0, true><<<ggrid, 256, 0, stream>>>(feature, 128, Wf2h_p, nullptr, buf192, 192, N);
  // fused prop over [uf|cond]: f2h -> catbuf[:, :128], Pc -> Pcbf
  prop192<<<(N + 7) / 8, 192, 0, stream>>>(buf192, catbuf, Pcbf, row_ptr, csr_src, dinv, b_f2h, N);
  // c2h = tanh(Pc @ W_c2h + b) -> catbuf[:, 128:256]
  gemm_mfma<64, 1, false><<<ggrid, 256, 0, stream>>>(Pcbf, 64, Wc2h_p, b_c2h, catbuf + 128, 256, N);
  // L2: u2 = catbuf @ W_h2h ; h = tanh(P(u2)+b) -> hbuf
  gemm_mfma<256, 0, false><<<ggrid, 256, 0, stream>>>(catbuf, 256, Wh2h_p, nullptr, bufU, 128, N);
  prop128<<<(N + 15) / 16, 256, 0, stream>>>(bufU, hbuf, row_ptr, csr_src, dinv, b_h2h, N);
  // L3: v = h @ [W_mean|W_logvar] ; out = P(v)+bcat fused with reparam
  gemm_mfma<128, 0, false><<<ggrid, 256, 0, stream>>>(hbuf, 128, Wcat_p, nullptr, bufU, 128, N);
  prop_fin_bf<<<(N + 15) / 16, 256, 0, stream>>>(bufU, row_ptr, csr_src, dinv, bcat, noise,
                                                 (float*)d_out, N);
}